// Round 2
// baseline (394.188 us; speedup 1.0000x reference)
//
#include <hip/hip_runtime.h>
#include <hip/hip_bf16.h>
#include <math.h>

#define BB 256
#define LL 50
#define IDIM 128
#define PDIM 64
#define DIM 192
#define NITEMS 50000
#define NOUT 49999
#define WSC 20.0f
#define EPS 1e-5f

// ---------------- row norms of emb ----------------
__global__ __launch_bounds__(256) void k_norms(const float* __restrict__ emb,
                                               float* __restrict__ scale,
                                               float* __restrict__ invn) {
    int row  = blockIdx.x * 4 + (threadIdx.x >> 6);
    int lane = threadIdx.x & 63;
    const float* p = emb + (size_t)row * IDIM;
    float a = p[lane], b = p[lane + 64];
    float s = a * a + b * b;
#pragma unroll
    for (int off = 32; off; off >>= 1) s += __shfl_xor(s, off);
    if (lane == 0) {
        float n = sqrtf(s);
        scale[row] = fminf(1.0f, 1.5f / fmaxf(n, 1e-7f));
        invn[row]  = (n > 0.f) ? 1.f / n : 0.f;
    }
}

__global__ __launch_bounds__(64) void k_pnorms(const float* __restrict__ pe,
                                               float* __restrict__ pscale) {
    int row = threadIdx.x;
    if (row > LL) return;
    float s = 0.f;
    const float* p = pe + row * PDIM;
    for (int d = 0; d < PDIM; ++d) { float v = p[d]; s += v * v; }
    float n = sqrtf(s);
    pscale[row] = fminf(1.0f, 1.5f / fmaxf(n, 1e-7f));
}

// ---------------- gather: build X = concat(emb_r[x], pos_r[pos]) ----------------
__global__ __launch_bounds__(256) void k_gather(const int* __restrict__ x, const int* __restrict__ pos,
                                                const float* __restrict__ emb, const float* __restrict__ pe,
                                                const float* __restrict__ scale, const float* __restrict__ pscale,
                                                float* __restrict__ X) {
    int b = blockIdx.x, t = threadIdx.x;
    __shared__ int   xi[LL], pi[LL];
    __shared__ float xs[LL], ps[LL];
    if (t < LL) {
        int v = x[b * LL + t];  xi[t] = v;  xs[t] = scale[v];
        int pv = pos[b * LL + t]; pi[t] = pv; ps[t] = pscale[pv];
    }
    __syncthreads();
    for (int e = t; e < LL * DIM; e += 256) {
        int l = e / DIM, d = e - l * DIM;
        float v;
        if (d < IDIM) v = emb[(size_t)xi[l] * IDIM + d] * xs[l];
        else          v = pe[pi[l] * PDIM + (d - IDIM)] * ps[l];
        X[(size_t)b * LL * DIM + e] = v;
    }
}

// ---------------- generic GEMM: (12800x192) @ (192x192) ----------------
// MODE 0: C = A@B                        (B row-major [k][n])
// MODE 1: C = relu(A@B^T + bias)
// MODE 2: C = A@B^T + bias + extra      (extra same shape as C)
// MODE 3: C = sigmoid(A@B^T + bias + extra[row/LL, :])   (g with GL broadcast)
template <int MODE>
__global__ __launch_bounds__(256) void k_gemm(const float* __restrict__ A, const float* __restrict__ Bm,
                                              const float* __restrict__ bias, const float* __restrict__ extra,
                                              float* __restrict__ C) {
    const int Mb = blockIdx.x % 200;
    const int Nb = blockIdx.x / 200;
    const int mbase = Mb * 64, nbase = Nb * 64;
    __shared__ float As[16][64];
    __shared__ float Bs[16][64];
    int t = threadIdx.x;
    int tx = t & 15, ty = t >> 4;
    int m0 = ty * 4, n0 = tx * 4;
    float acc[4][4] = {};
    for (int kt = 0; kt < DIM; kt += 16) {
        {   // A tile (transpose to [k][m])
            int m = t >> 2, k0 = (t & 3) * 4;
            float4 v = *(const float4*)(A + (size_t)(mbase + m) * DIM + kt + k0);
            As[k0][m] = v.x; As[k0 + 1][m] = v.y; As[k0 + 2][m] = v.z; As[k0 + 3][m] = v.w;
        }
        if (MODE == 0) {
            int k = t >> 4, nn = (t & 15) * 4;
            float4 v = *(const float4*)(Bm + (size_t)(kt + k) * DIM + nbase + nn);
            *(float4*)&Bs[k][nn] = v;
        } else {
            int n = t >> 2, k0 = (t & 3) * 4;
            float4 v = *(const float4*)(Bm + (size_t)(nbase + n) * DIM + kt + k0);
            Bs[k0][n] = v.x; Bs[k0 + 1][n] = v.y; Bs[k0 + 2][n] = v.z; Bs[k0 + 3][n] = v.w;
        }
        __syncthreads();
#pragma unroll
        for (int k = 0; k < 16; ++k) {
            float4 av = *(const float4*)&As[k][m0];
            float4 bv = *(const float4*)&Bs[k][n0];
            float a4[4] = {av.x, av.y, av.z, av.w};
            float b4[4] = {bv.x, bv.y, bv.z, bv.w};
#pragma unroll
            for (int i = 0; i < 4; ++i)
#pragma unroll
                for (int j = 0; j < 4; ++j) acc[i][j] += a4[i] * b4[j];
        }
        __syncthreads();
    }
#pragma unroll
    for (int i = 0; i < 4; ++i) {
        size_t gr = (size_t)(mbase + m0 + i);
        float4 ov;
        float  o4[4];
#pragma unroll
        for (int j = 0; j < 4; ++j) {
            int gc = nbase + n0 + j;
            float v = acc[i][j];
            if (MODE == 1)      v = fmaxf(v + bias[gc], 0.f);
            else if (MODE == 2) v = v + bias[gc] + extra[gr * DIM + gc];
            else if (MODE == 3) {
                float pre = v + bias[gc] + extra[(gr / LL) * DIM + gc];
                v = 1.f / (1.f + expf(-pre));
            }
            o4[j] = v;
        }
        ov.x = o4[0]; ov.y = o4[1]; ov.z = o4[2]; ov.w = o4[3];
        *(float4*)&C[gr * DIM + nbase + n0] = ov;
    }
}

// ---------------- additive attention scores + masked softmax ----------------
__global__ __launch_bounds__(256) void k_alpha(const float* __restrict__ Kg, const float* __restrict__ Qg,
                                               const int* __restrict__ x, const float* __restrict__ vbias,
                                               const float* __restrict__ vw0, float* __restrict__ Ab) {
    int b = blockIdx.x, t = threadIdx.x;
    __shared__ float Ks[LL][DIM];
    __shared__ float vb0[DIM], vw[DIM];
    __shared__ int   xs[64];
    for (int e = t; e < LL * DIM; e += 256) Ks[e / DIM][e % DIM] = Kg[(size_t)b * LL * DIM + e];
    if (t < DIM) { vb0[t] = vbias[t]; vw[t] = vw0[t]; }
    if (t < 64) xs[t] = (t < LL) ? x[b * LL + t] : 0;
    __syncthreads();
    int wave = t >> 6, lane = t & 63;
    const float NEG = -__builtin_inff();
    for (int i = wave; i < LL; i += 4) {
        const float* Qp = Qg + ((size_t)b * LL + i) * DIM;
        float q0 = Qp[lane], q1 = Qp[lane + 64], q2 = Qp[lane + 128];
        float aj = NEG;
        for (int j = 0; j < LL; ++j) {
            float p = fmaxf(Ks[j][lane] + q0 + vb0[lane], 0.f) * vw[lane]
                    + fmaxf(Ks[j][lane + 64] + q1 + vb0[lane + 64], 0.f) * vw[lane + 64]
                    + fmaxf(Ks[j][lane + 128] + q2 + vb0[lane + 128], 0.f) * vw[lane + 128];
#pragma unroll
            for (int off = 32; off; off >>= 1) p += __shfl_xor(p, off);
            if (lane == j) aj = p;
        }
        bool valid = (lane < LL) && (xs[lane] != 0);
        if (!valid) aj = NEG;
        float m = aj;
#pragma unroll
        for (int off = 32; off; off >>= 1) m = fmaxf(m, __shfl_xor(m, off));
        float e = valid ? expf(aj - m) : 0.f;
        float s = e;
#pragma unroll
        for (int off = 32; off; off >>= 1) s += __shfl_xor(s, off);
        float a = e / s;
        if (lane < LL) Ab[((size_t)b * LL + i) * LL + lane] = a;
    }
}

// ---------------- S = a @ x_ ----------------
__global__ __launch_bounds__(256) void k_attnS(const float* __restrict__ Ab, const float* __restrict__ X,
                                               float* __restrict__ Sb) {
    int b = blockIdx.x, t = threadIdx.x;
    __shared__ float As[LL][LL];
    __shared__ float Xs[LL][DIM];
    for (int e = t; e < LL * LL; e += 256) As[e / LL][e % LL] = Ab[(size_t)b * LL * LL + e];
    for (int e = t; e < LL * DIM; e += 256) Xs[e / DIM][e % DIM] = X[(size_t)b * LL * DIM + e];
    __syncthreads();
    for (int o = t; o < LL * DIM; o += 256) {
        int i = o / DIM, d = o - i * DIM;
        float s = 0.f;
#pragma unroll 5
        for (int j = 0; j < LL; ++j) s += As[i][j] * Xs[j][d];
        Sb[(size_t)b * LL * DIM + o] = s;
    }
}

// ---------------- LayerNorm (in place) ----------------
__global__ __launch_bounds__(64) void k_ln(float* __restrict__ S2, const float* __restrict__ g,
                                           const float* __restrict__ bta) {
    size_t row = blockIdx.x;
    float* p = S2 + row * DIM;
    int lane = threadIdx.x;
    float v0 = p[lane], v1 = p[lane + 64], v2 = p[lane + 128];
    float s = v0 + v1 + v2;
#pragma unroll
    for (int off = 32; off; off >>= 1) s += __shfl_xor(s, off);
    float mu = s * (1.f / DIM);
    float d0 = v0 - mu, d1 = v1 - mu, d2 = v2 - mu;
    float q = d0 * d0 + d1 * d1 + d2 * d2;
#pragma unroll
    for (int off = 32; off; off >>= 1) q += __shfl_xor(q, off);
    float inv = rsqrtf(q * (1.f / DIM) + EPS);
    p[lane]       = g[lane] * d0 * inv + bta[lane];
    p[lane + 64]  = g[lane + 64] * d1 * inv + bta[lane + 64];
    p[lane + 128] = g[lane + 128] * d2 * inv + bta[lane + 128];
}

// ---------------- st = sum_p wA[p] * S3[b,p,:] ----------------
__global__ __launch_bounds__(DIM) void k_st(const float* __restrict__ wA, const float* __restrict__ S3,
                                            float* __restrict__ ST) {
    int b = blockIdx.x, d = threadIdx.x;
    __shared__ float w[LL];
    if (d < LL) w[d] = wA[d];
    __syncthreads();
    float s = 0.f;
    for (int p = 0; p < LL; ++p) s += w[p] * S3[((size_t)b * LL + p) * DIM + d];
    ST[b * DIM + d] = s;
}

// ---------------- GL = x_[b,L-1,:] @ wg2^T + wg2_b ----------------
__global__ __launch_bounds__(DIM) void k_gl(const float* __restrict__ X, const float* __restrict__ wg2W,
                                            const float* __restrict__ wg2b, float* __restrict__ GL) {
    int b = blockIdx.x, j = threadIdx.x;
    __shared__ float xr[DIM];
    xr[j] = X[((size_t)b * LL + LL - 1) * DIM + j];
    __syncthreads();
    float s = wg2b[j];
    const float* wr = wg2W + (size_t)j * DIM;
#pragma unroll 4
    for (int d = 0; d < DIM; ++d) s += xr[d] * wr[d];
    GL[b * DIM + j] = s;
}

// ---------------- ag = g @ gq ----------------
__global__ __launch_bounds__(256) void k_ag(const float* __restrict__ G, const float* __restrict__ gq,
                                            float* __restrict__ AG) {
    int r = blockIdx.x * 4 + (threadIdx.x >> 6);
    int lane = threadIdx.x & 63;
    const float* p = G + (size_t)r * DIM;
    float s = p[lane] * gq[lane] + p[lane + 64] * gq[lane + 64] + p[lane + 128] * gq[lane + 128];
#pragma unroll
    for (int off = 32; off; off >>= 1) s += __shfl_xor(s, off);
    if (lane == 0) AG[r] = s;
}

// ---------------- sg = sum_l ag[l] * x_[b,l,:] ----------------
__global__ __launch_bounds__(DIM) void k_sg(const float* __restrict__ AG, const float* __restrict__ X,
                                            float* __restrict__ SG) {
    int b = blockIdx.x, d = threadIdx.x;
    __shared__ float a[LL];
    if (d < LL) a[d] = AG[b * LL + d];
    __syncthreads();
    float s = 0.f;
    for (int l = 0; l < LL; ++l) s += a[l] * X[((size_t)b * LL + l) * DIM + d];
    SG[b * DIM + d] = s;
}

// ---------------- c = normalize(selu([st,sl,sg] @ wf^T + wf_b)) ----------------
__global__ __launch_bounds__(DIM) void k_c(const float* __restrict__ ST, const float* __restrict__ X,
                                           const float* __restrict__ SG, const float* __restrict__ wfW,
                                           const float* __restrict__ wfb, float* __restrict__ Cb) {
    int b = blockIdx.x, t = threadIdx.x;
    __shared__ float v[3 * DIM];
    __shared__ float ssum[3];
    v[t]           = ST[b * DIM + t];
    v[DIM + t]     = X[((size_t)b * LL + LL - 1) * DIM + t];
    v[2 * DIM + t] = SG[b * DIM + t];
    __syncthreads();
    float cj = 0.f;
    if (t < IDIM) {
        float s = wfb[t];
        const float* wr = wfW + (size_t)t * (3 * DIM);
#pragma unroll 4
        for (int e = 0; e < 3 * DIM; ++e) s += v[e] * wr[e];
        const float sa = 1.6732632423543772f, sc = 1.0507009873554805f;
        cj = sc * (s > 0.f ? s : sa * expm1f(s));
    }
    float sq = cj * cj;
#pragma unroll
    for (int off = 32; off; off >>= 1) sq += __shfl_xor(sq, off);
    if ((t & 63) == 0) ssum[t >> 6] = sq;
    __syncthreads();
    if (t < IDIM) {
        float nrm = sqrtf(ssum[0] + ssum[1]);
        Cb[b * IDIM + t] = cj / nrm;
    }
}

// ---------------- Z = 20 * invn * (C @ emb[1:]^T) ----------------
__global__ __launch_bounds__(256) void k_z(const float* __restrict__ Cb, const float* __restrict__ emb,
                                           const float* __restrict__ invn, float* __restrict__ Z) {
    int bm = blockIdx.x & 3;
    int bn = blockIdx.x >> 2;
    int m1 = bm * 64, n1 = bn * 64;
    __shared__ float Ct[IDIM][64];
    __shared__ float Bt[IDIM][64];
    int t = threadIdx.x;
    {
        int m = t >> 2, k0 = (t & 3) * 32;
        const float4* src = (const float4*)(Cb + (size_t)(m1 + m) * IDIM + k0);
#pragma unroll
        for (int q = 0; q < 8; ++q) {
            float4 vv = src[q];
            int k = k0 + q * 4;
            Ct[k][m] = vv.x; Ct[k + 1][m] = vv.y; Ct[k + 2][m] = vv.z; Ct[k + 3][m] = vv.w;
        }
        int n = m;
        int gn = n1 + n;
        if (gn < NOUT) {
            const float4* bsrc = (const float4*)(emb + (size_t)(gn + 1) * IDIM + k0);
#pragma unroll
            for (int q = 0; q < 8; ++q) {
                float4 vv = bsrc[q];
                int k = k0 + q * 4;
                Bt[k][n] = vv.x; Bt[k + 1][n] = vv.y; Bt[k + 2][n] = vv.z; Bt[k + 3][n] = vv.w;
            }
        } else {
#pragma unroll
            for (int q = 0; q < 8; ++q) {
                int k = k0 + q * 4;
                Bt[k][n] = 0.f; Bt[k + 1][n] = 0.f; Bt[k + 2][n] = 0.f; Bt[k + 3][n] = 0.f;
            }
        }
    }
    __syncthreads();
    int tx = t & 15, ty = t >> 4;
    int m0 = ty * 4, n0 = tx * 4;
    float acc[4][4] = {};
#pragma unroll 4
    for (int k = 0; k < IDIM; ++k) {
        float4 av = *(const float4*)&Ct[k][m0];
        float4 bv = *(const float4*)&Bt[k][n0];
        float a4[4] = {av.x, av.y, av.z, av.w};
        float b4[4] = {bv.x, bv.y, bv.z, bv.w};
#pragma unroll
        for (int i = 0; i < 4; ++i)
#pragma unroll
            for (int j = 0; j < 4; ++j) acc[i][j] += a4[i] * b4[j];
    }
#pragma unroll
    for (int i = 0; i < 4; ++i) {
        size_t gm = (size_t)(m1 + m0 + i);
#pragma unroll
        for (int j = 0; j < 4; ++j) {
            int gn = n1 + n0 + j;
            if (gn < NOUT) Z[gm * NOUT + gn] = WSC * invn[gn + 1] * acc[i][j];
        }
    }
}

extern "C" void kernel_launch(void* const* d_in, const int* in_sizes, int n_in,
                              void* d_out, int out_size, void* d_ws, size_t ws_size,
                              hipStream_t stream) {
    const int*   x     = (const int*)d_in[0];
    const int*   pos   = (const int*)d_in[1];
    const float* emb   = (const float*)d_in[2];
    const float* pose  = (const float*)d_in[3];
    const float* vw0   = (const float*)d_in[4];
    const float* vw1   = (const float*)d_in[5];
    const float* vw2   = (const float*)d_in[6];
    const float* vbias = (const float*)d_in[7];
    const float* w1W   = (const float*)d_in[8];
    const float* w1b   = (const float*)d_in[9];
    const float* w2W   = (const float*)d_in[10];
    const float* w2b   = (const float*)d_in[11];
    const float* wA    = (const float*)d_in[12];
    const float* wg1W  = (const float*)d_in[13];
    const float* wg1b  = (const float*)d_in[14];
    const float* wg2W  = (const float*)d_in[15];
    const float* wg2b  = (const float*)d_in[16];
    const float* gq    = (const float*)d_in[17];
    const float* wfW   = (const float*)d_in[18];
    const float* wfb   = (const float*)d_in[19];
    const float* lng   = (const float*)d_in[20];
    const float* lnb   = (const float*)d_in[21];
    float* Z = (float*)d_out;

    float* w = (float*)d_ws;
    float* scale  = w; w += NITEMS;
    float* invn   = w; w += NITEMS;
    float* pscale = w; w += 64;
    float* X  = w; w += (size_t)BB * LL * DIM;
    float* Kb = w; w += (size_t)BB * LL * DIM;   // reused as H2
    float* Qb = w; w += (size_t)BB * LL * DIM;   // reused as S2 / S3
    float* Sb = w; w += (size_t)BB * LL * DIM;   // reused as G
    float* Ab = w; w += (size_t)BB * LL * LL;
    float* AG = w; w += BB * LL;
    float* GL = w; w += BB * DIM;
    float* ST = w; w += BB * DIM;
    float* SG = w; w += BB * DIM;
    float* Cb = w; w += BB * IDIM;

    k_norms<<<NITEMS / 4, 256, 0, stream>>>(emb, scale, invn);
    k_pnorms<<<1, 64, 0, stream>>>(pose, pscale);
    k_gather<<<BB, 256, 0, stream>>>(x, pos, emb, pose, scale, pscale, X);
    k_gemm<0><<<600, 256, 0, stream>>>(X, vw1, nullptr, nullptr, Kb);
    k_gemm<0><<<600, 256, 0, stream>>>(X, vw2, nullptr, nullptr, Qb);
    k_alpha<<<BB, 256, 0, stream>>>(Kb, Qb, x, vbias, vw0, Ab);
    k_attnS<<<BB, 256, 0, stream>>>(Ab, X, Sb);
    k_gemm<1><<<600, 256, 0, stream>>>(Sb, w1W, w1b, nullptr, Kb);            // H2
    k_gemm<2><<<600, 256, 0, stream>>>(Kb, w2W, w2b, Sb, Qb);                 // S2
    k_ln<<<BB * LL, 64, 0, stream>>>(Qb, lng, lnb);                           // S3 in place
    k_st<<<BB, DIM, 0, stream>>>(wA, Qb, ST);
    k_gl<<<BB, DIM, 0, stream>>>(X, wg2W, wg2b, GL);
    k_gemm<3><<<600, 256, 0, stream>>>(X, wg1W, wg1b, GL, Sb);                // G
    k_ag<<<BB * LL / 4, 256, 0, stream>>>(Sb, gq, AG);
    k_sg<<<BB, DIM, 0, stream>>>(AG, X, SG);
    k_c<<<BB, DIM, 0, stream>>>(ST, X, SG, wfW, wfb, Cb);
    k_z<<<(NOUT + 63) / 64 * 4, 256, 0, stream>>>(Cb, emb, invn, Z);
}

// Round 6
// 306.309 us; speedup vs baseline: 1.2869x; 1.2869x over previous
//
#include <hip/hip_runtime.h>
#include <hip/hip_bf16.h>
#include <math.h>

#define BB 256
#define LL 50
#define IDIM 128
#define PDIM 64
#define DIM 192
#define NITEMS 50000
#define NOUT 49999
#define WSC 20.0f
#define EPS 1e-5f

// ---------------- row norms of emb ----------------
__global__ __launch_bounds__(256) void k_norms(const float* __restrict__ emb,
                                               float* __restrict__ scale,
                                               float* __restrict__ invn) {
    int row  = blockIdx.x * 4 + (threadIdx.x >> 6);
    int lane = threadIdx.x & 63;
    const float* p = emb + (size_t)row * IDIM;
    float a = p[lane], b = p[lane + 64];
    float s = a * a + b * b;
#pragma unroll
    for (int off = 32; off; off >>= 1) s += __shfl_xor(s, off);
    if (lane == 0) {
        float n = sqrtf(s);
        scale[row] = fminf(1.0f, 1.5f / fmaxf(n, 1e-7f));
        invn[row]  = (n > 0.f) ? 1.f / n : 0.f;
    }
}

__global__ __launch_bounds__(64) void k_pnorms(const float* __restrict__ pe,
                                               float* __restrict__ pscale) {
    int row = threadIdx.x;
    if (row > LL) return;
    float s = 0.f;
    const float* p = pe + row * PDIM;
    for (int d = 0; d < PDIM; ++d) { float v = p[d]; s += v * v; }
    float n = sqrtf(s);
    pscale[row] = fminf(1.0f, 1.5f / fmaxf(n, 1e-7f));
}

// ---------------- gather: build X = concat(emb_r[x], pos_r[pos]) ----------------
__global__ __launch_bounds__(256) void k_gather(const int* __restrict__ x, const int* __restrict__ pos,
                                                const float* __restrict__ emb, const float* __restrict__ pe,
                                                const float* __restrict__ scale, const float* __restrict__ pscale,
                                                float* __restrict__ X) {
    int b = blockIdx.x, t = threadIdx.x;
    __shared__ int   xi[LL], pi[LL];
    __shared__ float xs[LL], ps[LL];
    if (t < LL) {
        int v = x[b * LL + t];  xi[t] = v;  xs[t] = scale[v];
        int pv = pos[b * LL + t]; pi[t] = pv; ps[t] = pscale[pv];
    }
    __syncthreads();
    for (int e = t; e < LL * DIM; e += 256) {
        int l = e / DIM, d = e - l * DIM;
        float v;
        if (d < IDIM) v = emb[(size_t)xi[l] * IDIM + d] * xs[l];
        else          v = pe[pi[l] * PDIM + (d - IDIM)] * ps[l];
        X[(size_t)b * LL * DIM + e] = v;
    }
}

// ---------------- generic GEMM: (12800x192) @ (192x192) ----------------
// MODE 0: C = A@B                        (B row-major [k][n])
// MODE 1: C = relu(A@B^T + bias)
// MODE 2: C = A@B^T + bias + extra      (extra same shape as C)
// MODE 3: C = sigmoid(A@B^T + bias + extra[row/LL, :])   (g with GL broadcast)
// MODE 4: C = A@B + bias                (K' with vbias folded)
template <int MODE>
__global__ __launch_bounds__(256) void k_gemm(const float* __restrict__ A, const float* __restrict__ Bm,
                                              const float* __restrict__ bias, const float* __restrict__ extra,
                                              float* __restrict__ C) {
    const int Mb = blockIdx.x % 200;
    const int Nb = blockIdx.x / 200;
    const int mbase = Mb * 64, nbase = Nb * 64;
    __shared__ float As[16][64];
    __shared__ float Bs[16][64];
    int t = threadIdx.x;
    int tx = t & 15, ty = t >> 4;
    int m0 = ty * 4, n0 = tx * 4;
    float acc[4][4] = {};
    for (int kt = 0; kt < DIM; kt += 16) {
        {   // A tile (transpose to [k][m])
            int m = t >> 2, k0 = (t & 3) * 4;
            float4 v = *(const float4*)(A + (size_t)(mbase + m) * DIM + kt + k0);
            As[k0][m] = v.x; As[k0 + 1][m] = v.y; As[k0 + 2][m] = v.z; As[k0 + 3][m] = v.w;
        }
        if (MODE == 0 || MODE == 4) {
            int k = t >> 4, nn = (t & 15) * 4;
            float4 v = *(const float4*)(Bm + (size_t)(kt + k) * DIM + nbase + nn);
            *(float4*)&Bs[k][nn] = v;
        } else {
            int n = t >> 2, k0 = (t & 3) * 4;
            float4 v = *(const float4*)(Bm + (size_t)(nbase + n) * DIM + kt + k0);
            Bs[k0][n] = v.x; Bs[k0 + 1][n] = v.y; Bs[k0 + 2][n] = v.z; Bs[k0 + 3][n] = v.w;
        }
        __syncthreads();
#pragma unroll
        for (int k = 0; k < 16; ++k) {
            float4 av = *(const float4*)&As[k][m0];
            float4 bv = *(const float4*)&Bs[k][n0];
            float a4[4] = {av.x, av.y, av.z, av.w};
            float b4[4] = {bv.x, bv.y, bv.z, bv.w};
#pragma unroll
            for (int i = 0; i < 4; ++i)
#pragma unroll
                for (int j = 0; j < 4; ++j) acc[i][j] += a4[i] * b4[j];
        }
        __syncthreads();
    }
#pragma unroll
    for (int i = 0; i < 4; ++i) {
        size_t gr = (size_t)(mbase + m0 + i);
        float4 ov;
        float  o4[4];
#pragma unroll
        for (int j = 0; j < 4; ++j) {
            int gc = nbase + n0 + j;
            float v = acc[i][j];
            if (MODE == 1)      v = fmaxf(v + bias[gc], 0.f);
            else if (MODE == 2) v = v + bias[gc] + extra[gr * DIM + gc];
            else if (MODE == 3) {
                float pre = v + bias[gc] + extra[(gr / LL) * DIM + gc];
                v = 1.f / (1.f + expf(-pre));
            }
            else if (MODE == 4) v = v + bias[gc];
            o4[j] = v;
        }
        ov.x = o4[0]; ov.y = o4[1]; ov.z = o4[2]; ov.w = o4[3];
        *(float4*)&C[gr * DIM + nbase + n0] = ov;
    }
}

// ---------------- additive attention scores + masked softmax (v2) ----------------
// alpha[b,i,j] = sum_d relu(K'[b,j,d] + Q[b,i,d]) * vw0[d]   (vbias folded into K')
// Block = (b, half): 25 i-rows. Wave w owns d-slice [48w,48w+48).
// Lane j register-caches K'[j, slice]; Q tile staged in LDS (broadcast reads).
__global__ __launch_bounds__(256) void k_alpha2(const float* __restrict__ Kp, const float* __restrict__ Qg,
                                                const int* __restrict__ x, const float* __restrict__ vw0,
                                                float* __restrict__ Ab) {
    int b    = blockIdx.x >> 1;
    int i0   = (blockIdx.x & 1) * 25;
    int t    = threadIdx.x;
    int wave = t >> 6, lane = t & 63;
    int d0   = wave * 48;

    __shared__ float Qs[25 * DIM];            // rows i0..i0+24, contiguous
    __shared__ float parts[4][25][64];
    __shared__ int   xs[64];

    // stage Q tile (contiguous 4800 floats)
    const float4* Qbase = (const float4*)(Qg + ((size_t)b * LL + i0) * DIM);
    for (int e = t; e < 25 * DIM / 4; e += 256) ((float4*)Qs)[e] = Qbase[e];
    if (t < 64) xs[t] = (t < LL) ? x[b * LL + t] : 0;

    // register-cache K' slice and vw0 slice
    float kr[48], wr[48];
    {
        const float* wp = vw0 + d0;
#pragma unroll
        for (int q = 0; q < 12; ++q) {
            float4 v = *(const float4*)(wp + q * 4);
            wr[q * 4] = v.x; wr[q * 4 + 1] = v.y; wr[q * 4 + 2] = v.z; wr[q * 4 + 3] = v.w;
        }
        if (lane < LL) {
            const float* kp = Kp + ((size_t)b * LL + lane) * DIM + d0;
#pragma unroll
            for (int q = 0; q < 12; ++q) {
                float4 v = *(const float4*)(kp + q * 4);
                kr[q * 4] = v.x; kr[q * 4 + 1] = v.y; kr[q * 4 + 2] = v.z; kr[q * 4 + 3] = v.w;
            }
        } else {
#pragma unroll
            for (int q = 0; q < 48; ++q) kr[q] = 0.f;
        }
    }
    __syncthreads();

    // main: per i-row, serial d in registers, lane-parallel over j
    for (int i = 0; i < 25; ++i) {
        const float* qrow = &Qs[i * DIM + d0];
        float acc = 0.f;
#pragma unroll
        for (int q = 0; q < 12; ++q) {
            float4 qv = *(const float4*)(qrow + q * 4);
            acc += fmaxf(kr[q * 4 + 0] + qv.x, 0.f) * wr[q * 4 + 0];
            acc += fmaxf(kr[q * 4 + 1] + qv.y, 0.f) * wr[q * 4 + 1];
            acc += fmaxf(kr[q * 4 + 2] + qv.z, 0.f) * wr[q * 4 + 2];
            acc += fmaxf(kr[q * 4 + 3] + qv.w, 0.f) * wr[q * 4 + 3];
        }
        parts[wave][i][lane] = acc;
    }
    __syncthreads();

    // masked softmax, one row per wave-iteration
    const float NEG = -__builtin_inff();
    bool valid = (lane < LL) && (xs[lane] != 0);
    for (int i = wave; i < 25; i += 4) {
        float aj = parts[0][i][lane] + parts[1][i][lane] + parts[2][i][lane] + parts[3][i][lane];
        if (!valid) aj = NEG;
        float m = aj;
#pragma unroll
        for (int off = 32; off; off >>= 1) m = fmaxf(m, __shfl_xor(m, off));
        float e = valid ? expf(aj - m) : 0.f;
        float s = e;
#pragma unroll
        for (int off = 32; off; off >>= 1) s += __shfl_xor(s, off);
        if (lane < LL) Ab[((size_t)b * LL + i0 + i) * LL + lane] = e / s;
    }
}

// ---------------- S = a @ x_ ----------------
__global__ __launch_bounds__(256) void k_attnS(const float* __restrict__ Ab, const float* __restrict__ X,
                                               float* __restrict__ Sb) {
    int b = blockIdx.x, t = threadIdx.x;
    __shared__ float As[LL][LL];
    __shared__ float Xs[LL][DIM];
    for (int e = t; e < LL * LL; e += 256) As[e / LL][e % LL] = Ab[(size_t)b * LL * LL + e];
    for (int e = t; e < LL * DIM; e += 256) Xs[e / DIM][e % DIM] = X[(size_t)b * LL * DIM + e];
    __syncthreads();
    for (int o = t; o < LL * DIM; o += 256) {
        int i = o / DIM, d = o - i * DIM;
        float s = 0.f;
#pragma unroll 5
        for (int j = 0; j < LL; ++j) s += As[i][j] * Xs[j][d];
        Sb[(size_t)b * LL * DIM + o] = s;
    }
}

// ---------------- LayerNorm (in place) ----------------
__global__ __launch_bounds__(64) void k_ln(float* __restrict__ S2, const float* __restrict__ g,
                                           const float* __restrict__ bta) {
    size_t row = blockIdx.x;
    float* p = S2 + row * DIM;
    int lane = threadIdx.x;
    float v0 = p[lane], v1 = p[lane + 64], v2 = p[lane + 128];
    float s = v0 + v1 + v2;
#pragma unroll
    for (int off = 32; off; off >>= 1) s += __shfl_xor(s, off);
    float mu = s * (1.f / DIM);
    float d0 = v0 - mu, d1 = v1 - mu, d2 = v2 - mu;
    float q = d0 * d0 + d1 * d1 + d2 * d2;
#pragma unroll
    for (int off = 32; off; off >>= 1) q += __shfl_xor(q, off);
    float inv = rsqrtf(q * (1.f / DIM) + EPS);
    p[lane]       = g[lane] * d0 * inv + bta[lane];
    p[lane + 64]  = g[lane + 64] * d1 * inv + bta[lane + 64];
    p[lane + 128] = g[lane + 128] * d2 * inv + bta[lane + 128];
}

// ---------------- st = sum_p wA[p] * S3[b,p,:] ----------------
__global__ __launch_bounds__(DIM) void k_st(const float* __restrict__ wA, const float* __restrict__ S3,
                                            float* __restrict__ ST) {
    int b = blockIdx.x, d = threadIdx.x;
    __shared__ float w[LL];
    if (d < LL) w[d] = wA[d];
    __syncthreads();
    float s = 0.f;
    for (int p = 0; p < LL; ++p) s += w[p] * S3[((size_t)b * LL + p) * DIM + d];
    ST[b * DIM + d] = s;
}

// ---------------- GL = x_[b,L-1,:] @ wg2^T + wg2_b ----------------
__global__ __launch_bounds__(DIM) void k_gl(const float* __restrict__ X, const float* __restrict__ wg2W,
                                            const float* __restrict__ wg2b, float* __restrict__ GL) {
    int b = blockIdx.x, j = threadIdx.x;
    __shared__ float xr[DIM];
    xr[j] = X[((size_t)b * LL + LL - 1) * DIM + j];
    __syncthreads();
    float s = wg2b[j];
    const float* wr = wg2W + (size_t)j * DIM;
#pragma unroll 4
    for (int d = 0; d < DIM; ++d) s += xr[d] * wr[d];
    GL[b * DIM + j] = s;
}

// ---------------- ag = g @ gq ----------------
__global__ __launch_bounds__(256) void k_ag(const float* __restrict__ G, const float* __restrict__ gq,
                                            float* __restrict__ AG) {
    int r = blockIdx.x * 4 + (threadIdx.x >> 6);
    int lane = threadIdx.x & 63;
    const float* p = G + (size_t)r * DIM;
    float s = p[lane] * gq[lane] + p[lane + 64] * gq[lane + 64] + p[lane + 128] * gq[lane + 128];
#pragma unroll
    for (int off = 32; off; off >>= 1) s += __shfl_xor(s, off);
    if (lane == 0) AG[r] = s;
}

// ---------------- sg = sum_l ag[l] * x_[b,l,:] ----------------
__global__ __launch_bounds__(DIM) void k_sg(const float* __restrict__ AG, const float* __restrict__ X,
                                            float* __restrict__ SG) {
    int b = blockIdx.x, d = threadIdx.x;
    __shared__ float a[LL];
    if (d < LL) a[d] = AG[b * LL + d];
    __syncthreads();
    float s = 0.f;
    for (int l = 0; l < LL; ++l) s += a[l] * X[((size_t)b * LL + l) * DIM + d];
    SG[b * DIM + d] = s;
}

// ---------------- c = normalize(selu([st,sl,sg] @ wf^T + wf_b)) ----------------
__global__ __launch_bounds__(DIM) void k_c(const float* __restrict__ ST, const float* __restrict__ X,
                                           const float* __restrict__ SG, const float* __restrict__ wfW,
                                           const float* __restrict__ wfb, float* __restrict__ Cb) {
    int b = blockIdx.x, t = threadIdx.x;
    __shared__ float v[3 * DIM];
    __shared__ float ssum[3];
    v[t]           = ST[b * DIM + t];
    v[DIM + t]     = X[((size_t)b * LL + LL - 1) * DIM + t];
    v[2 * DIM + t] = SG[b * DIM + t];
    __syncthreads();
    float cj = 0.f;
    if (t < IDIM) {
        float s = wfb[t];
        const float* wr = wfW + (size_t)t * (3 * DIM);
#pragma unroll 4
        for (int e = 0; e < 3 * DIM; ++e) s += v[e] * wr[e];
        const float sa = 1.6732632423543772f, sc = 1.0507009873554805f;
        cj = sc * (s > 0.f ? s : sa * expm1f(s));
    }
    float sq = cj * cj;
#pragma unroll
    for (int off = 32; off; off >>= 1) sq += __shfl_xor(sq, off);
    if ((t & 63) == 0) ssum[t >> 6] = sq;
    __syncthreads();
    if (t < IDIM) {
        float nrm = sqrtf(ssum[0] + ssum[1]);
        Cb[b * IDIM + t] = cj / nrm;
    }
}

// ---------------- Z = 20 * invn * (C @ emb[1:]^T), 128x128 tiles ----------------
__global__ __launch_bounds__(256) void k_z2(const float* __restrict__ Cb, const float* __restrict__ emb,
                                            const float* __restrict__ invn, float* __restrict__ Z) {
    int bm = blockIdx.x & 1;
    int bn = blockIdx.x >> 1;
    int m1 = bm * 128, n1 = bn * 128;
    __shared__ float As[16][128];
    __shared__ float Bs[16][128];
    int t = threadIdx.x;
    int tx = t & 15, ty = t >> 4;
    int m0 = ty * 8, n0 = tx * 8;
    int lr = t >> 1;              // 0..127: row within tile
    int k0 = (t & 1) * 8;         // 0 or 8
    float acc[8][8] = {};
    for (int kt = 0; kt < IDIM; kt += 16) {
        {   // A tile: Cb rows m1..m1+127, cols kt+k0..+7 (transposed store)
            const float* src = Cb + (size_t)(m1 + lr) * IDIM + kt + k0;
            float4 v0 = *(const float4*)(src);
            float4 v1 = *(const float4*)(src + 4);
            As[k0 + 0][lr] = v0.x; As[k0 + 1][lr] = v0.y; As[k0 + 2][lr] = v0.z; As[k0 + 3][lr] = v0.w;
            As[k0 + 4][lr] = v1.x; As[k0 + 5][lr] = v1.y; As[k0 + 6][lr] = v1.z; As[k0 + 7][lr] = v1.w;
        }
        {   // B tile: emb rows 1+n1+lr
            int gn = n1 + lr;
            if (gn < NOUT) {
                const float* src = emb + (size_t)(gn + 1) * IDIM + kt + k0;
                float4 v0 = *(const float4*)(src);
                float4 v1 = *(const float4*)(src + 4);
                Bs[k0 + 0][lr] = v0.x; Bs[k0 + 1][lr] = v0.y; Bs[k0 + 2][lr] = v0.z; Bs[k0 + 3][lr] = v0.w;
                Bs[k0 + 4][lr] = v1.x; Bs[k0 + 5][lr] = v1.y; Bs[k0 + 6][lr] = v1.z; Bs[k0 + 7][lr] = v1.w;
            } else {
#pragma unroll
                for (int q = 0; q < 8; ++q) Bs[k0 + q][lr] = 0.f;
            }
        }
        __syncthreads();
#pragma unroll
        for (int k = 0; k < 16; ++k) {
            float4 a0 = *(const float4*)&As[k][m0];
            float4 a1 = *(const float4*)&As[k][m0 + 4];
            float4 b0 = *(const float4*)&Bs[k][n0];
            float4 b1 = *(const float4*)&Bs[k][n0 + 4];
            float a8[8] = {a0.x, a0.y, a0.z, a0.w, a1.x, a1.y, a1.z, a1.w};
            float b8[8] = {b0.x, b0.y, b0.z, b0.w, b1.x, b1.y, b1.z, b1.w};
#pragma unroll
            for (int i = 0; i < 8; ++i)
#pragma unroll
                for (int j = 0; j < 8; ++j) acc[i][j] += a8[i] * b8[j];
        }
        __syncthreads();
    }
    // epilogue: scale by 20*invn[gn+1], guarded stores on last n-tile
    float sc[8];
#pragma unroll
    for (int j = 0; j < 8; ++j) {
        int gn = n1 + n0 + j;
        sc[j] = (gn < NOUT) ? WSC * invn[gn + 1] : 0.f;
    }
    bool full = (n1 + n0 + 7) < NOUT;
#pragma unroll
    for (int i = 0; i < 8; ++i) {
        size_t gm = (size_t)(m1 + m0 + i);
        float* dst = Z + gm * NOUT + n1 + n0;
        if (full) {
            float4 o0, o1;
            o0.x = acc[i][0] * sc[0]; o0.y = acc[i][1] * sc[1];
            o0.z = acc[i][2] * sc[2]; o0.w = acc[i][3] * sc[3];
            o1.x = acc[i][4] * sc[4]; o1.y = acc[i][5] * sc[5];
            o1.z = acc[i][6] * sc[6]; o1.w = acc[i][7] * sc[7];
            *(float4*)(dst)     = o0;
            *(float4*)(dst + 4) = o1;
        } else {
#pragma unroll
            for (int j = 0; j < 8; ++j) {
                int gn = n1 + n0 + j;
                if (gn < NOUT) dst[j] = acc[i][j] * sc[j];
            }
        }
    }
}

extern "C" void kernel_launch(void* const* d_in, const int* in_sizes, int n_in,
                              void* d_out, int out_size, void* d_ws, size_t ws_size,
                              hipStream_t stream) {
    const int*   x     = (const int*)d_in[0];
    const int*   pos   = (const int*)d_in[1];
    const float* emb   = (const float*)d_in[2];
    const float* pose  = (const float*)d_in[3];
    const float* vw0   = (const float*)d_in[4];
    const float* vw1   = (const float*)d_in[5];
    const float* vw2   = (const float*)d_in[6];
    const float* vbias = (const float*)d_in[7];
    const float* w1W   = (const float*)d_in[8];
    const float* w1b   = (const float*)d_in[9];
    const float* w2W   = (const float*)d_in[10];
    const float* w2b   = (const float*)d_in[11];
    const float* wA    = (const float*)d_in[12];
    const float* wg1W  = (const float*)d_in[13];
    const float* wg1b  = (const float*)d_in[14];
    const float* wg2W  = (const float*)d_in[15];
    const float* wg2b  = (const float*)d_in[16];
    const float* gq    = (const float*)d_in[17];
    const float* wfW   = (const float*)d_in[18];
    const float* wfb   = (const float*)d_in[19];
    const float* lng   = (const float*)d_in[20];
    const float* lnb   = (const float*)d_in[21];
    float* Z = (float*)d_out;

    float* w = (float*)d_ws;
    float* scale  = w; w += NITEMS;
    float* invn   = w; w += NITEMS;
    float* pscale = w; w += 64;
    float* X  = w; w += (size_t)BB * LL * DIM;
    float* Kb = w; w += (size_t)BB * LL * DIM;   // K' (vbias folded); reused as H2
    float* Qb = w; w += (size_t)BB * LL * DIM;   // Q; reused as S2 / S3
    float* Sb = w; w += (size_t)BB * LL * DIM;   // S; reused as G
    float* Ab = w; w += (size_t)BB * LL * LL;
    float* AG = w; w += BB * LL;
    float* GL = w; w += BB * DIM;
    float* ST = w; w += BB * DIM;
    float* SG = w; w += BB * DIM;
    float* Cb = w; w += BB * IDIM;

    k_norms<<<NITEMS / 4, 256, 0, stream>>>(emb, scale, invn);
    k_pnorms<<<1, 64, 0, stream>>>(pose, pscale);
    k_gather<<<BB, 256, 0, stream>>>(x, pos, emb, pose, scale, pscale, X);
    k_gemm<4><<<600, 256, 0, stream>>>(X, vw1, vbias, nullptr, Kb);           // K' = X@vw1 + vbias
    k_gemm<0><<<600, 256, 0, stream>>>(X, vw2, nullptr, nullptr, Qb);         // Q  = X@vw2
    k_alpha2<<<BB * 2, 256, 0, stream>>>(Kb, Qb, x, vw0, Ab);
    k_attnS<<<BB, 256, 0, stream>>>(Ab, X, Sb);
    k_gemm<1><<<600, 256, 0, stream>>>(Sb, w1W, w1b, nullptr, Kb);            // H2
    k_gemm<2><<<600, 256, 0, stream>>>(Kb, w2W, w2b, Sb, Qb);                 // S2
    k_ln<<<BB * LL, 64, 0, stream>>>(Qb, lng, lnb);                           // S3 in place
    k_st<<<BB, DIM, 0, stream>>>(wA, Qb, ST);
    k_gl<<<BB, DIM, 0, stream>>>(X, wg2W, wg2b, GL);
    k_gemm<3><<<600, 256, 0, stream>>>(X, wg1W, wg1b, GL, Sb);                // G
    k_ag<<<BB * LL / 4, 256, 0, stream>>>(Sb, gq, AG);
    k_sg<<<BB, DIM, 0, stream>>>(AG, X, SG);
    k_c<<<BB, DIM, 0, stream>>>(ST, X, SG, wfW, wfb, Cb);
    k_z2<<<((NOUT + 127) / 128) * 2, 256, 0, stream>>>(Cb, emb, invn, Z);
}

// Round 7
// 285.482 us; speedup vs baseline: 1.3808x; 1.0730x over previous
//
#include <hip/hip_runtime.h>
#include <hip/hip_bf16.h>
#include <math.h>
#include <stdint.h>

#define BB 256
#define LL 50
#define IDIM 128
#define PDIM 64
#define DIM 192
#define NITEMS 50000
#define NOUT 49999
#define WSC 20.0f
#define EPS 1e-5f

typedef __attribute__((ext_vector_type(8))) short  short8;
typedef __attribute__((ext_vector_type(8))) unsigned short ushort8v;
typedef __attribute__((ext_vector_type(4))) float  f32x4;

// ---------------- row norms of emb ----------------
__global__ __launch_bounds__(256) void k_norms(const float* __restrict__ emb,
                                               float* __restrict__ scale,
                                               float* __restrict__ invn) {
    int row  = blockIdx.x * 4 + (threadIdx.x >> 6);
    int lane = threadIdx.x & 63;
    const float* p = emb + (size_t)row * IDIM;
    float a = p[lane], b = p[lane + 64];
    float s = a * a + b * b;
#pragma unroll
    for (int off = 32; off; off >>= 1) s += __shfl_xor(s, off);
    if (lane == 0) {
        float n = sqrtf(s);
        scale[row] = fminf(1.0f, 1.5f / fmaxf(n, 1e-7f));
        invn[row]  = (n > 0.f) ? 1.f / n : 0.f;
    }
}

__global__ __launch_bounds__(64) void k_pnorms(const float* __restrict__ pe,
                                               float* __restrict__ pscale) {
    int row = threadIdx.x;
    if (row > LL) return;
    float s = 0.f;
    const float* p = pe + row * PDIM;
    for (int d = 0; d < PDIM; ++d) { float v = p[d]; s += v * v; }
    float n = sqrtf(s);
    pscale[row] = fminf(1.0f, 1.5f / fmaxf(n, 1e-7f));
}

// ---------------- gather: build X = concat(emb_r[x], pos_r[pos]) ----------------
__global__ __launch_bounds__(256) void k_gather(const int* __restrict__ x, const int* __restrict__ pos,
                                                const float* __restrict__ emb, const float* __restrict__ pe,
                                                const float* __restrict__ scale, const float* __restrict__ pscale,
                                                float* __restrict__ X) {
    int b = blockIdx.x, t = threadIdx.x;
    __shared__ int   xi[LL], pi[LL];
    __shared__ float xs[LL], ps[LL];
    if (t < LL) {
        int v = x[b * LL + t];  xi[t] = v;  xs[t] = scale[v];
        int pv = pos[b * LL + t]; pi[t] = pv; ps[t] = pscale[pv];
    }
    __syncthreads();
    for (int e = t; e < LL * DIM; e += 256) {
        int l = e / DIM, d = e - l * DIM;
        float v;
        if (d < IDIM) v = emb[(size_t)xi[l] * IDIM + d] * xs[l];
        else          v = pe[pi[l] * PDIM + (d - IDIM)] * ps[l];
        X[(size_t)b * LL * DIM + e] = v;
    }
}

// ---------------- generic GEMM: (12800x192) @ (192x192) ----------------
template <int MODE>
__global__ __launch_bounds__(256) void k_gemm(const float* __restrict__ A, const float* __restrict__ Bm,
                                              const float* __restrict__ bias, const float* __restrict__ extra,
                                              float* __restrict__ C) {
    const int Mb = blockIdx.x % 200;
    const int Nb = blockIdx.x / 200;
    const int mbase = Mb * 64, nbase = Nb * 64;
    __shared__ float As[16][64];
    __shared__ float Bs[16][64];
    int t = threadIdx.x;
    int tx = t & 15, ty = t >> 4;
    int m0 = ty * 4, n0 = tx * 4;
    float acc[4][4] = {};
    for (int kt = 0; kt < DIM; kt += 16) {
        {
            int m = t >> 2, k0 = (t & 3) * 4;
            float4 v = *(const float4*)(A + (size_t)(mbase + m) * DIM + kt + k0);
            As[k0][m] = v.x; As[k0 + 1][m] = v.y; As[k0 + 2][m] = v.z; As[k0 + 3][m] = v.w;
        }
        if (MODE == 0 || MODE == 4) {
            int k = t >> 4, nn = (t & 15) * 4;
            float4 v = *(const float4*)(Bm + (size_t)(kt + k) * DIM + nbase + nn);
            *(float4*)&Bs[k][nn] = v;
        } else {
            int n = t >> 2, k0 = (t & 3) * 4;
            float4 v = *(const float4*)(Bm + (size_t)(nbase + n) * DIM + kt + k0);
            Bs[k0][n] = v.x; Bs[k0 + 1][n] = v.y; Bs[k0 + 2][n] = v.z; Bs[k0 + 3][n] = v.w;
        }
        __syncthreads();
#pragma unroll
        for (int k = 0; k < 16; ++k) {
            float4 av = *(const float4*)&As[k][m0];
            float4 bv = *(const float4*)&Bs[k][n0];
            float a4[4] = {av.x, av.y, av.z, av.w};
            float b4[4] = {bv.x, bv.y, bv.z, bv.w};
#pragma unroll
            for (int i = 0; i < 4; ++i)
#pragma unroll
                for (int j = 0; j < 4; ++j) acc[i][j] += a4[i] * b4[j];
        }
        __syncthreads();
    }
#pragma unroll
    for (int i = 0; i < 4; ++i) {
        size_t gr = (size_t)(mbase + m0 + i);
        float4 ov;
        float  o4[4];
#pragma unroll
        for (int j = 0; j < 4; ++j) {
            int gc = nbase + n0 + j;
            float v = acc[i][j];
            if (MODE == 1)      v = fmaxf(v + bias[gc], 0.f);
            else if (MODE == 2) v = v + bias[gc] + extra[gr * DIM + gc];
            else if (MODE == 3) {
                float pre = v + bias[gc] + extra[(gr / LL) * DIM + gc];
                v = 1.f / (1.f + expf(-pre));
            }
            else if (MODE == 4) v = v + bias[gc];
            o4[j] = v;
        }
        ov.x = o4[0]; ov.y = o4[1]; ov.z = o4[2]; ov.w = o4[3];
        *(float4*)&C[gr * DIM + nbase + n0] = ov;
    }
}

// ---------------- additive attention scores + masked softmax (v2) ----------------
__global__ __launch_bounds__(256) void k_alpha2(const float* __restrict__ Kp, const float* __restrict__ Qg,
                                                const int* __restrict__ x, const float* __restrict__ vw0,
                                                float* __restrict__ Ab) {
    int b    = blockIdx.x >> 1;
    int i0   = (blockIdx.x & 1) * 25;
    int t    = threadIdx.x;
    int wave = t >> 6, lane = t & 63;
    int d0   = wave * 48;

    __shared__ float Qs[25 * DIM];
    __shared__ float parts[4][25][64];
    __shared__ int   xs[64];

    const float4* Qbase = (const float4*)(Qg + ((size_t)b * LL + i0) * DIM);
    for (int e = t; e < 25 * DIM / 4; e += 256) ((float4*)Qs)[e] = Qbase[e];
    if (t < 64) xs[t] = (t < LL) ? x[b * LL + t] : 0;

    float kr[48], wr[48];
    {
        const float* wp = vw0 + d0;
#pragma unroll
        for (int q = 0; q < 12; ++q) {
            float4 v = *(const float4*)(wp + q * 4);
            wr[q * 4] = v.x; wr[q * 4 + 1] = v.y; wr[q * 4 + 2] = v.z; wr[q * 4 + 3] = v.w;
        }
        if (lane < LL) {
            const float* kp = Kp + ((size_t)b * LL + lane) * DIM + d0;
#pragma unroll
            for (int q = 0; q < 12; ++q) {
                float4 v = *(const float4*)(kp + q * 4);
                kr[q * 4] = v.x; kr[q * 4 + 1] = v.y; kr[q * 4 + 2] = v.z; kr[q * 4 + 3] = v.w;
            }
        } else {
#pragma unroll
            for (int q = 0; q < 48; ++q) kr[q] = 0.f;
        }
    }
    __syncthreads();

    for (int i = 0; i < 25; ++i) {
        const float* qrow = &Qs[i * DIM + d0];
        float acc = 0.f;
#pragma unroll
        for (int q = 0; q < 12; ++q) {
            float4 qv = *(const float4*)(qrow + q * 4);
            acc += fmaxf(kr[q * 4 + 0] + qv.x, 0.f) * wr[q * 4 + 0];
            acc += fmaxf(kr[q * 4 + 1] + qv.y, 0.f) * wr[q * 4 + 1];
            acc += fmaxf(kr[q * 4 + 2] + qv.z, 0.f) * wr[q * 4 + 2];
            acc += fmaxf(kr[q * 4 + 3] + qv.w, 0.f) * wr[q * 4 + 3];
        }
        parts[wave][i][lane] = acc;
    }
    __syncthreads();

    const float NEG = -__builtin_inff();
    bool valid = (lane < LL) && (xs[lane] != 0);
    for (int i = wave; i < 25; i += 4) {
        float aj = parts[0][i][lane] + parts[1][i][lane] + parts[2][i][lane] + parts[3][i][lane];
        if (!valid) aj = NEG;
        float m = aj;
#pragma unroll
        for (int off = 32; off; off >>= 1) m = fmaxf(m, __shfl_xor(m, off));
        float e = valid ? expf(aj - m) : 0.f;
        float s = e;
#pragma unroll
        for (int off = 32; off; off >>= 1) s += __shfl_xor(s, off);
        if (lane < LL) Ab[((size_t)b * LL + i0 + i) * LL + lane] = e / s;
    }
}

// ---------------- S = a @ x_ ----------------
__global__ __launch_bounds__(256) void k_attnS(const float* __restrict__ Ab, const float* __restrict__ X,
                                               float* __restrict__ Sb) {
    int b = blockIdx.x, t = threadIdx.x;
    __shared__ float As[LL][LL];
    __shared__ float Xs[LL][DIM];
    for (int e = t; e < LL * LL; e += 256) As[e / LL][e % LL] = Ab[(size_t)b * LL * LL + e];
    for (int e = t; e < LL * DIM; e += 256) Xs[e / DIM][e % DIM] = X[(size_t)b * LL * DIM + e];
    __syncthreads();
    for (int o = t; o < LL * DIM; o += 256) {
        int i = o / DIM, d = o - i * DIM;
        float s = 0.f;
#pragma unroll 5
        for (int j = 0; j < LL; ++j) s += As[i][j] * Xs[j][d];
        Sb[(size_t)b * LL * DIM + o] = s;
    }
}

// ---------------- LayerNorm (in place) ----------------
__global__ __launch_bounds__(64) void k_ln(float* __restrict__ S2, const float* __restrict__ g,
                                           const float* __restrict__ bta) {
    size_t row = blockIdx.x;
    float* p = S2 + row * DIM;
    int lane = threadIdx.x;
    float v0 = p[lane], v1 = p[lane + 64], v2 = p[lane + 128];
    float s = v0 + v1 + v2;
#pragma unroll
    for (int off = 32; off; off >>= 1) s += __shfl_xor(s, off);
    float mu = s * (1.f / DIM);
    float d0 = v0 - mu, d1 = v1 - mu, d2 = v2 - mu;
    float q = d0 * d0 + d1 * d1 + d2 * d2;
#pragma unroll
    for (int off = 32; off; off >>= 1) q += __shfl_xor(q, off);
    float inv = rsqrtf(q * (1.f / DIM) + EPS);
    p[lane]       = g[lane] * d0 * inv + bta[lane];
    p[lane + 64]  = g[lane + 64] * d1 * inv + bta[lane + 64];
    p[lane + 128] = g[lane + 128] * d2 * inv + bta[lane + 128];
}

// ---------------- st = sum_p wA[p] * S3[b,p,:] ----------------
__global__ __launch_bounds__(DIM) void k_st(const float* __restrict__ wA, const float* __restrict__ S3,
                                            float* __restrict__ ST) {
    int b = blockIdx.x, d = threadIdx.x;
    __shared__ float w[LL];
    if (d < LL) w[d] = wA[d];
    __syncthreads();
    float s = 0.f;
    for (int p = 0; p < LL; ++p) s += w[p] * S3[((size_t)b * LL + p) * DIM + d];
    ST[b * DIM + d] = s;
}

// ---------------- GL = x_[b,L-1,:] @ wg2^T + wg2_b ----------------
__global__ __launch_bounds__(DIM) void k_gl(const float* __restrict__ X, const float* __restrict__ wg2W,
                                            const float* __restrict__ wg2b, float* __restrict__ GL) {
    int b = blockIdx.x, j = threadIdx.x;
    __shared__ float xr[DIM];
    xr[j] = X[((size_t)b * LL + LL - 1) * DIM + j];
    __syncthreads();
    float s = wg2b[j];
    const float* wr = wg2W + (size_t)j * DIM;
#pragma unroll 4
    for (int d = 0; d < DIM; ++d) s += xr[d] * wr[d];
    GL[b * DIM + j] = s;
}

// ---------------- ag = g @ gq ----------------
__global__ __launch_bounds__(256) void k_ag(const float* __restrict__ G, const float* __restrict__ gq,
                                            float* __restrict__ AG) {
    int r = blockIdx.x * 4 + (threadIdx.x >> 6);
    int lane = threadIdx.x & 63;
    const float* p = G + (size_t)r * DIM;
    float s = p[lane] * gq[lane] + p[lane + 64] * gq[lane + 64] + p[lane + 128] * gq[lane + 128];
#pragma unroll
    for (int off = 32; off; off >>= 1) s += __shfl_xor(s, off);
    if (lane == 0) AG[r] = s;
}

// ---------------- sg = sum_l ag[l] * x_[b,l,:] ----------------
__global__ __launch_bounds__(DIM) void k_sg(const float* __restrict__ AG, const float* __restrict__ X,
                                            float* __restrict__ SG) {
    int b = blockIdx.x, d = threadIdx.x;
    __shared__ float a[LL];
    if (d < LL) a[d] = AG[b * LL + d];
    __syncthreads();
    float s = 0.f;
    for (int l = 0; l < LL; ++l) s += a[l] * X[((size_t)b * LL + l) * DIM + d];
    SG[b * DIM + d] = s;
}

// ---------------- c = normalize(selu([st,sl,sg] @ wf^T + wf_b)) ----------------
__global__ __launch_bounds__(DIM) void k_c(const float* __restrict__ ST, const float* __restrict__ X,
                                           const float* __restrict__ SG, const float* __restrict__ wfW,
                                           const float* __restrict__ wfb, float* __restrict__ Cb) {
    int b = blockIdx.x, t = threadIdx.x;
    __shared__ float v[3 * DIM];
    __shared__ float ssum[3];
    v[t]           = ST[b * DIM + t];
    v[DIM + t]     = X[((size_t)b * LL + LL - 1) * DIM + t];
    v[2 * DIM + t] = SG[b * DIM + t];
    __syncthreads();
    float cj = 0.f;
    if (t < IDIM) {
        float s = wfb[t];
        const float* wr = wfW + (size_t)t * (3 * DIM);
#pragma unroll 4
        for (int e = 0; e < 3 * DIM; ++e) s += v[e] * wr[e];
        const float sa = 1.6732632423543772f, sc = 1.0507009873554805f;
        cj = sc * (s > 0.f ? s : sa * expm1f(s));
    }
    float sq = cj * cj;
#pragma unroll
    for (int off = 32; off; off >>= 1) sq += __shfl_xor(sq, off);
    if ((t & 63) == 0) ssum[t >> 6] = sq;
    __syncthreads();
    if (t < IDIM) {
        float nrm = sqrtf(ssum[0] + ssum[1]);
        Cb[b * IDIM + t] = cj / nrm;
    }
}

// ---------------- f32 -> bf16 (RNE) conversion, 8 elems/thread ----------------
__device__ __forceinline__ unsigned short f2bf(float f) {
    unsigned int u = __float_as_uint(f);
    u = (u + 0x7FFFu + ((u >> 16) & 1u)) >> 16;
    return (unsigned short)u;
}
__global__ __launch_bounds__(256) void k_cvt(const float* __restrict__ src,
                                             unsigned short* __restrict__ dst, int n8) {
    int i = blockIdx.x * 256 + threadIdx.x;
    if (i >= n8) return;
    const float4* s = (const float4*)(src + (size_t)i * 8);
    float4 v0 = s[0], v1 = s[1];
    ushort8v o;
    o[0] = f2bf(v0.x); o[1] = f2bf(v0.y); o[2] = f2bf(v0.z); o[3] = f2bf(v0.w);
    o[4] = f2bf(v1.x); o[5] = f2bf(v1.y); o[6] = f2bf(v1.z); o[7] = f2bf(v1.w);
    *(ushort8v*)(dst + (size_t)i * 8) = o;
}

// ---------------- Z via bf16 MFMA: block = 128m x 128n, no LDS ----------------
// D(16x16) = A(16x32) * B(32x16), A row=lane&15 k-chunk=lane>>4; B col=lane&15 same k-chunk.
// C/D: col=lane&15, row=(lane>>4)*4+reg  [verified layout]
__global__ __launch_bounds__(256) void k_z3(const unsigned short* __restrict__ Cb16,
                                            const unsigned short* __restrict__ emb16,
                                            const float* __restrict__ invn,
                                            float* __restrict__ Z) {
    int m_base = (blockIdx.x & 1) * 128;
    int n_base = (blockIdx.x >> 1) * 128;
    int t = threadIdx.x;
    int w = t >> 6, l = t & 63;
    int lr = l & 15, lk = l >> 4;

    // A frags in registers: 2 m-tiles per wave x 4 k-steps
    short8 a[2][4];
#pragma unroll
    for (int m2 = 0; m2 < 2; ++m2) {
        int mrow = m_base + (w * 2 + m2) * 16 + lr;
        const unsigned short* ap = Cb16 + (size_t)mrow * IDIM + lk * 8;
        a[m2][0] = *(const short8*)(ap);
        a[m2][1] = *(const short8*)(ap + 32);
        a[m2][2] = *(const short8*)(ap + 64);
        a[m2][3] = *(const short8*)(ap + 96);
    }
    f32x4 acc[2][8] = {};
#pragma unroll
    for (int nt = 0; nt < 8; ++nt) {
        int nrow = n_base + nt * 16 + lr;
        short8 bfr[4];
        if (nrow < NOUT) {
            const unsigned short* bp = emb16 + (size_t)(nrow + 1) * IDIM + lk * 8;
            bfr[0] = *(const short8*)(bp);
            bfr[1] = *(const short8*)(bp + 32);
            bfr[2] = *(const short8*)(bp + 64);
            bfr[3] = *(const short8*)(bp + 96);
        } else {
            short8 z = {};
            bfr[0] = z; bfr[1] = z; bfr[2] = z; bfr[3] = z;
        }
#pragma unroll
        for (int m2 = 0; m2 < 2; ++m2)
#pragma unroll
            for (int ks = 0; ks < 4; ++ks)
                acc[m2][nt] = __builtin_amdgcn_mfma_f32_16x16x32_bf16(a[m2][ks], bfr[ks], acc[m2][nt], 0, 0, 0);
    }
    // epilogue: scale 20*invn, scattered-guarded stores
#pragma unroll
    for (int nt = 0; nt < 8; ++nt) {
        int gn = n_base + nt * 16 + lr;
        if (gn >= NOUT) continue;
        float sc = WSC * invn[gn + 1];
#pragma unroll
        for (int m2 = 0; m2 < 2; ++m2) {
            int mrow = m_base + (w * 2 + m2) * 16 + lk * 4;
#pragma unroll
            for (int r = 0; r < 4; ++r)
                Z[(size_t)(mrow + r) * NOUT + gn] = acc[m2][nt][r] * sc;
        }
    }
}

// ---------------- fallback f32 Z (kept from r5) ----------------
__global__ __launch_bounds__(256) void k_z2(const float* __restrict__ Cb, const float* __restrict__ emb,
                                            const float* __restrict__ invn, float* __restrict__ Z) {
    int bm = blockIdx.x & 1;
    int bn = blockIdx.x >> 1;
    int m1 = bm * 128, n1 = bn * 128;
    __shared__ float As[16][128];
    __shared__ float Bs[16][128];
    int t = threadIdx.x;
    int tx = t & 15, ty = t >> 4;
    int m0 = ty * 8, n0 = tx * 8;
    int lr = t >> 1;
    int k0 = (t & 1) * 8;
    float acc[8][8] = {};
    for (int kt = 0; kt < IDIM; kt += 16) {
        {
            const float* src = Cb + (size_t)(m1 + lr) * IDIM + kt + k0;
            float4 v0 = *(const float4*)(src);
            float4 v1 = *(const float4*)(src + 4);
            As[k0 + 0][lr] = v0.x; As[k0 + 1][lr] = v0.y; As[k0 + 2][lr] = v0.z; As[k0 + 3][lr] = v0.w;
            As[k0 + 4][lr] = v1.x; As[k0 + 5][lr] = v1.y; As[k0 + 6][lr] = v1.z; As[k0 + 7][lr] = v1.w;
        }
        {
            int gn = n1 + lr;
            if (gn < NOUT) {
                const float* src = emb + (size_t)(gn + 1) * IDIM + kt + k0;
                float4 v0 = *(const float4*)(src);
                float4 v1 = *(const float4*)(src + 4);
                Bs[k0 + 0][lr] = v0.x; Bs[k0 + 1][lr] = v0.y; Bs[k0 + 2][lr] = v0.z; Bs[k0 + 3][lr] = v0.w;
                Bs[k0 + 4][lr] = v1.x; Bs[k0 + 5][lr] = v1.y; Bs[k0 + 6][lr] = v1.z; Bs[k0 + 7][lr] = v1.w;
            } else {
#pragma unroll
                for (int q = 0; q < 8; ++q) Bs[k0 + q][lr] = 0.f;
            }
        }
        __syncthreads();
#pragma unroll
        for (int k = 0; k < 16; ++k) {
            float4 a0 = *(const float4*)&As[k][m0];
            float4 a1 = *(const float4*)&As[k][m0 + 4];
            float4 b0 = *(const float4*)&Bs[k][n0];
            float4 b1 = *(const float4*)&Bs[k][n0 + 4];
            float a8[8] = {a0.x, a0.y, a0.z, a0.w, a1.x, a1.y, a1.z, a1.w};
            float b8[8] = {b0.x, b0.y, b0.z, b0.w, b1.x, b1.y, b1.z, b1.w};
#pragma unroll
            for (int i = 0; i < 8; ++i)
#pragma unroll
                for (int j = 0; j < 8; ++j) acc[i][j] += a8[i] * b8[j];
        }
        __syncthreads();
    }
    float sc[8];
#pragma unroll
    for (int j = 0; j < 8; ++j) {
        int gn = n1 + n0 + j;
        sc[j] = (gn < NOUT) ? WSC * invn[gn + 1] : 0.f;
    }
    bool full = (n1 + n0 + 7) < NOUT;
#pragma unroll
    for (int i = 0; i < 8; ++i) {
        size_t gm = (size_t)(m1 + m0 + i);
        float* dst = Z + gm * NOUT + n1 + n0;
        if (full) {
            float4 o0, o1;
            o0.x = acc[i][0] * sc[0]; o0.y = acc[i][1] * sc[1];
            o0.z = acc[i][2] * sc[2]; o0.w = acc[i][3] * sc[3];
            o1.x = acc[i][4] * sc[4]; o1.y = acc[i][5] * sc[5];
            o1.z = acc[i][6] * sc[6]; o1.w = acc[i][7] * sc[7];
            *(float4*)(dst)     = o0;
            *(float4*)(dst + 4) = o1;
        } else {
#pragma unroll
            for (int j = 0; j < 8; ++j) {
                int gn = n1 + n0 + j;
                if (gn < NOUT) dst[j] = acc[i][j] * sc[j];
            }
        }
    }
}

extern "C" void kernel_launch(void* const* d_in, const int* in_sizes, int n_in,
                              void* d_out, int out_size, void* d_ws, size_t ws_size,
                              hipStream_t stream) {
    const int*   x     = (const int*)d_in[0];
    const int*   pos   = (const int*)d_in[1];
    const float* emb   = (const float*)d_in[2];
    const float* pose  = (const float*)d_in[3];
    const float* vw0   = (const float*)d_in[4];
    const float* vw1   = (const float*)d_in[5];
    const float* vw2   = (const float*)d_in[6];
    const float* vbias = (const float*)d_in[7];
    const float* w1W   = (const float*)d_in[8];
    const float* w1b   = (const float*)d_in[9];
    const float* w2W   = (const float*)d_in[10];
    const float* w2b   = (const float*)d_in[11];
    const float* wA    = (const float*)d_in[12];
    const float* wg1W  = (const float*)d_in[13];
    const float* wg1b  = (const float*)d_in[14];
    const float* wg2W  = (const float*)d_in[15];
    const float* wg2b  = (const float*)d_in[16];
    const float* gq    = (const float*)d_in[17];
    const float* wfW   = (const float*)d_in[18];
    const float* wfb   = (const float*)d_in[19];
    const float* lng   = (const float*)d_in[20];
    const float* lnb   = (const float*)d_in[21];
    float* Z = (float*)d_out;

    float* w = (float*)d_ws;
    float* scale  = w; w += NITEMS;
    float* invn   = w; w += NITEMS;
    float* pscale = w; w += 64;
    float* X  = w; w += (size_t)BB * LL * DIM;
    float* Kb = w; w += (size_t)BB * LL * DIM;   // K' (vbias folded); reused as H2
    float* Qb = w; w += (size_t)BB * LL * DIM;   // Q; reused as S2 / S3
    float* Sb = w; w += (size_t)BB * LL * DIM;   // S; reused as G
    float* Ab = w; w += (size_t)BB * LL * LL;
    float* AG = w; w += BB * LL;
    float* GL = w; w += BB * DIM;
    float* ST = w; w += BB * DIM;
    float* SG = w; w += BB * DIM;
    float* Cb = w; w += BB * IDIM;
    // bf16 scratch (16B aligned)
    w = (float*)(((uintptr_t)w + 15) & ~(uintptr_t)15);
    unsigned short* emb16 = (unsigned short*)w; w += (size_t)NITEMS * IDIM / 2;
    unsigned short* Cb16  = (unsigned short*)w; w += (size_t)BB * IDIM / 2;
    bool use_mfma = ((char*)w - (char*)d_ws) <= (ptrdiff_t)ws_size;

    k_norms<<<NITEMS / 4, 256, 0, stream>>>(emb, scale, invn);
    k_pnorms<<<1, 64, 0, stream>>>(pose, pscale);
    if (use_mfma)
        k_cvt<<<(NITEMS * IDIM / 8 + 255) / 256, 256, 0, stream>>>(emb, emb16, NITEMS * IDIM / 8);
    k_gather<<<BB, 256, 0, stream>>>(x, pos, emb, pose, scale, pscale, X);
    k_gemm<4><<<600, 256, 0, stream>>>(X, vw1, vbias, nullptr, Kb);           // K' = X@vw1 + vbias
    k_gemm<0><<<600, 256, 0, stream>>>(X, vw2, nullptr, nullptr, Qb);         // Q  = X@vw2
    k_alpha2<<<BB * 2, 256, 0, stream>>>(Kb, Qb, x, vw0, Ab);
    k_attnS<<<BB, 256, 0, stream>>>(Ab, X, Sb);
    k_gemm<1><<<600, 256, 0, stream>>>(Sb, w1W, w1b, nullptr, Kb);            // H2
    k_gemm<2><<<600, 256, 0, stream>>>(Kb, w2W, w2b, Sb, Qb);                 // S2
    k_ln<<<BB * LL, 64, 0, stream>>>(Qb, lng, lnb);                           // S3 in place
    k_st<<<BB, DIM, 0, stream>>>(wA, Qb, ST);
    k_gl<<<BB, DIM, 0, stream>>>(X, wg2W, wg2b, GL);
    k_gemm<3><<<600, 256, 0, stream>>>(X, wg1W, wg1b, GL, Sb);                // G
    k_ag<<<BB * LL / 4, 256, 0, stream>>>(Sb, gq, AG);
    k_sg<<<BB, DIM, 0, stream>>>(AG, X, SG);
    k_c<<<BB, DIM, 0, stream>>>(ST, X, SG, wfW, wfb, Cb);
    if (use_mfma) {
        k_cvt<<<(BB * IDIM / 8 + 255) / 256, 256, 0, stream>>>(Cb, Cb16, BB * IDIM / 8);
        k_z3<<<((NOUT + 127) / 128) * 2, 256, 0, stream>>>(Cb16, emb16, invn, Z);
    } else {
        k_z2<<<((NOUT + 127) / 128) * 2, 256, 0, stream>>>(Cb, emb, invn, Z);
    }
}

// Round 8
// 245.671 us; speedup vs baseline: 1.6045x; 1.1620x over previous
//
#include <hip/hip_runtime.h>
#include <hip/hip_bf16.h>
#include <math.h>
#include <stdint.h>

#define BB 256
#define LL 50
#define IDIM 128
#define PDIM 64
#define DIM 192
#define NITEMS 50000
#define NOUT 49999
#define WSC 20.0f
#define EPS 1e-5f

typedef __attribute__((ext_vector_type(8))) short  short8;
typedef __attribute__((ext_vector_type(4))) float  f32x4;

__device__ __forceinline__ unsigned short f2bf(float f) {
    unsigned int u = __float_as_uint(f);
    u = (u + 0x7FFFu + ((u >> 16) & 1u)) >> 16;
    return (unsigned short)u;
}

// ---------------- row norms of emb + bf16 copy ----------------
__global__ __launch_bounds__(256) void k_norms(const float* __restrict__ emb,
                                               float* __restrict__ scale,
                                               float* __restrict__ invn,
                                               unsigned short* __restrict__ emb16) {
    int row  = blockIdx.x * 4 + (threadIdx.x >> 6);
    int lane = threadIdx.x & 63;
    const float* p = emb + (size_t)row * IDIM;
    float a = p[lane], b = p[lane + 64];
    emb16[(size_t)row * IDIM + lane]      = f2bf(a);
    emb16[(size_t)row * IDIM + lane + 64] = f2bf(b);
    float s = a * a + b * b;
#pragma unroll
    for (int off = 32; off; off >>= 1) s += __shfl_xor(s, off);
    if (lane == 0) {
        float n = sqrtf(s);
        scale[row] = fminf(1.0f, 1.5f / fmaxf(n, 1e-7f));
        invn[row]  = (n > 0.f) ? 1.f / n : 0.f;
    }
}

__global__ __launch_bounds__(64) void k_pnorms(const float* __restrict__ pe,
                                               float* __restrict__ pscale) {
    int row = threadIdx.x;
    if (row > LL) return;
    float s = 0.f;
    const float* p = pe + row * PDIM;
    for (int d = 0; d < PDIM; ++d) { float v = p[d]; s += v * v; }
    float n = sqrtf(s);
    pscale[row] = fminf(1.0f, 1.5f / fmaxf(n, 1e-7f));
}

// ---------------- weight convert (+transpose for vw1,vw2) ----------------
// layout in Wout: [0]=vw1^T [1]=vw2^T [2]=w1W [3]=w2W [4]=wg1W, each 192*192
__global__ __launch_bounds__(256) void k_cvtw(const float* __restrict__ vw1, const float* __restrict__ vw2,
                                              const float* __restrict__ w1W, const float* __restrict__ w2W,
                                              const float* __restrict__ wg1W,
                                              unsigned short* __restrict__ Wout) {
    int b = blockIdx.x;
    int wi = b / 144;
    int pos = (b % 144) * 256 + threadIdx.x;     // 0..36863
    int n = pos / DIM, k = pos - n * DIM;
    float v;
    if      (wi == 0) v = vw1[(size_t)k * DIM + n];
    else if (wi == 1) v = vw2[(size_t)k * DIM + n];
    else if (wi == 2) v = w1W[pos];
    else if (wi == 3) v = w2W[pos];
    else              v = wg1W[pos];
    Wout[(size_t)wi * DIM * DIM + pos] = f2bf(v);
}

// ---------------- gather: X f32 + X bf16 ----------------
__global__ __launch_bounds__(256) void k_gather(const int* __restrict__ x, const int* __restrict__ pos,
                                                const float* __restrict__ emb, const float* __restrict__ pe,
                                                const float* __restrict__ scale, const float* __restrict__ pscale,
                                                float* __restrict__ X, unsigned short* __restrict__ X16) {
    int b = blockIdx.x, t = threadIdx.x;
    __shared__ int   xi[LL], pi[LL];
    __shared__ float xs[LL], ps[LL];
    if (t < LL) {
        int v = x[b * LL + t];  xi[t] = v;  xs[t] = scale[v];
        int pv = pos[b * LL + t]; pi[t] = pv; ps[t] = pscale[pv];
    }
    __syncthreads();
    for (int e = t; e < LL * DIM; e += 256) {
        int l = e / DIM, d = e - l * DIM;
        float v;
        if (d < IDIM) v = emb[(size_t)xi[l] * IDIM + d] * xs[l];
        else          v = pe[pi[l] * PDIM + (d - IDIM)] * ps[l];
        X[(size_t)b * LL * DIM + e]  = v;
        X16[(size_t)b * LL * DIM + e] = f2bf(v);
    }
}

// ---------------- bf16 MFMA GEMM: (12800x192) @ B[n][k]^T-layout (192x192) ----------------
// MODE 0: C = A@W            (f32 out)
// MODE 1: C = relu(A@W + b)  (bf16 out)
// MODE 2: C = A@W + b + extra           (f32 out)
// MODE 3: C = sigmoid(A@W + b + extra[row/LL,:]) (f32 out)
// MODE 4: C = A@W + b        (f32 out)
template <int MODE>
__global__ __launch_bounds__(256) void k_gemm16(const unsigned short* __restrict__ A16,
                                                const unsigned short* __restrict__ B16,
                                                const float* __restrict__ bias,
                                                const float* __restrict__ extra,
                                                void* __restrict__ Cout) {
    int mb = blockIdx.x % 200, nb = blockIdx.x / 200;
    int mbase = mb * 64, nbase = nb * 64;
    int t = threadIdx.x, w = t >> 6, l = t & 63;
    int lr = l & 15, lk = l >> 4;
    int arow = mbase + w * 16 + lr;
    const unsigned short* ap = A16 + (size_t)arow * DIM + lk * 8;
    short8 a[6];
#pragma unroll
    for (int ks = 0; ks < 6; ++ks) a[ks] = *(const short8*)(ap + ks * 32);
    f32x4 acc[4] = {};
#pragma unroll
    for (int nt = 0; nt < 4; ++nt) {
        int ncol = nbase + nt * 16 + lr;
        const unsigned short* bp = B16 + (size_t)ncol * DIM + lk * 8;
#pragma unroll
        for (int ks = 0; ks < 6; ++ks) {
            short8 bfr = *(const short8*)(bp + ks * 32);
            acc[nt] = __builtin_amdgcn_mfma_f32_16x16x32_bf16(a[ks], bfr, acc[nt], 0, 0, 0);
        }
    }
#pragma unroll
    for (int nt = 0; nt < 4; ++nt) {
        int gc = nbase + nt * 16 + lr;
        float bia = (MODE == 0) ? 0.f : bias[gc];
#pragma unroll
        for (int r = 0; r < 4; ++r) {
            int gr = mbase + w * 16 + lk * 4 + r;
            float v = acc[nt][r] + bia;
            if (MODE == 1)      v = fmaxf(v, 0.f);
            else if (MODE == 2) v += extra[(size_t)gr * DIM + gc];
            else if (MODE == 3) { v += extra[(size_t)(gr / LL) * DIM + gc]; v = 1.f / (1.f + expf(-v)); }
            if (MODE == 1) ((unsigned short*)Cout)[(size_t)gr * DIM + gc] = f2bf(v);
            else           ((float*)Cout)[(size_t)gr * DIM + gc] = v;
        }
    }
}

// ---------------- additive attention scores + masked softmax ----------------
__global__ __launch_bounds__(256) void k_alpha2(const float* __restrict__ Kp, const float* __restrict__ Qg,
                                                const int* __restrict__ x, const float* __restrict__ vw0,
                                                float* __restrict__ Ab) {
    int b    = blockIdx.x >> 1;
    int i0   = (blockIdx.x & 1) * 25;
    int t    = threadIdx.x;
    int wave = t >> 6, lane = t & 63;
    int d0   = wave * 48;

    __shared__ float Qs[25 * DIM];
    __shared__ float parts[4][25][64];
    __shared__ int   xs[64];

    const float4* Qbase = (const float4*)(Qg + ((size_t)b * LL + i0) * DIM);
    for (int e = t; e < 25 * DIM / 4; e += 256) ((float4*)Qs)[e] = Qbase[e];
    if (t < 64) xs[t] = (t < LL) ? x[b * LL + t] : 0;

    float kr[48], wr[48];
    {
        const float* wp = vw0 + d0;
#pragma unroll
        for (int q = 0; q < 12; ++q) {
            float4 v = *(const float4*)(wp + q * 4);
            wr[q * 4] = v.x; wr[q * 4 + 1] = v.y; wr[q * 4 + 2] = v.z; wr[q * 4 + 3] = v.w;
        }
        if (lane < LL) {
            const float* kp = Kp + ((size_t)b * LL + lane) * DIM + d0;
#pragma unroll
            for (int q = 0; q < 12; ++q) {
                float4 v = *(const float4*)(kp + q * 4);
                kr[q * 4] = v.x; kr[q * 4 + 1] = v.y; kr[q * 4 + 2] = v.z; kr[q * 4 + 3] = v.w;
            }
        } else {
#pragma unroll
            for (int q = 0; q < 48; ++q) kr[q] = 0.f;
        }
    }
    __syncthreads();

    for (int i = 0; i < 25; ++i) {
        const float* qrow = &Qs[i * DIM + d0];
        float acc = 0.f;
#pragma unroll
        for (int q = 0; q < 12; ++q) {
            float4 qv = *(const float4*)(qrow + q * 4);
            acc += fmaxf(kr[q * 4 + 0] + qv.x, 0.f) * wr[q * 4 + 0];
            acc += fmaxf(kr[q * 4 + 1] + qv.y, 0.f) * wr[q * 4 + 1];
            acc += fmaxf(kr[q * 4 + 2] + qv.z, 0.f) * wr[q * 4 + 2];
            acc += fmaxf(kr[q * 4 + 3] + qv.w, 0.f) * wr[q * 4 + 3];
        }
        parts[wave][i][lane] = acc;
    }
    __syncthreads();

    const float NEG = -__builtin_inff();
    bool valid = (lane < LL) && (xs[lane] != 0);
    for (int i = wave; i < 25; i += 4) {
        float aj = parts[0][i][lane] + parts[1][i][lane] + parts[2][i][lane] + parts[3][i][lane];
        if (!valid) aj = NEG;
        float m = aj;
#pragma unroll
        for (int off = 32; off; off >>= 1) m = fmaxf(m, __shfl_xor(m, off));
        float e = valid ? expf(aj - m) : 0.f;
        float s = e;
#pragma unroll
        for (int off = 32; off; off >>= 1) s += __shfl_xor(s, off);
        if (lane < LL) Ab[((size_t)b * LL + i0 + i) * LL + lane] = e / s;
    }
}

// ---------------- S = a @ x_  (f32 + bf16 out) ----------------
__global__ __launch_bounds__(256) void k_attnS(const float* __restrict__ Ab, const float* __restrict__ X,
                                               float* __restrict__ Sb, unsigned short* __restrict__ S16) {
    int b = blockIdx.x, t = threadIdx.x;
    __shared__ float As[LL][LL];
    __shared__ float Xs[LL][DIM];
    for (int e = t; e < LL * LL; e += 256) As[e / LL][e % LL] = Ab[(size_t)b * LL * LL + e];
    for (int e = t; e < LL * DIM; e += 256) Xs[e / DIM][e % DIM] = X[(size_t)b * LL * DIM + e];
    __syncthreads();
    for (int o = t; o < LL * DIM; o += 256) {
        int i = o / DIM, d = o - i * DIM;
        float s = 0.f;
#pragma unroll 5
        for (int j = 0; j < LL; ++j) s += As[i][j] * Xs[j][d];
        Sb[(size_t)b * LL * DIM + o]  = s;
        S16[(size_t)b * LL * DIM + o] = f2bf(s);
    }
}

// ---------------- LayerNorm (in place) ----------------
__global__ __launch_bounds__(64) void k_ln(float* __restrict__ S2, const float* __restrict__ g,
                                           const float* __restrict__ bta) {
    size_t row = blockIdx.x;
    float* p = S2 + row * DIM;
    int lane = threadIdx.x;
    float v0 = p[lane], v1 = p[lane + 64], v2 = p[lane + 128];
    float s = v0 + v1 + v2;
#pragma unroll
    for (int off = 32; off; off >>= 1) s += __shfl_xor(s, off);
    float mu = s * (1.f / DIM);
    float d0 = v0 - mu, d1 = v1 - mu, d2 = v2 - mu;
    float q = d0 * d0 + d1 * d1 + d2 * d2;
#pragma unroll
    for (int off = 32; off; off >>= 1) q += __shfl_xor(q, off);
    float inv = rsqrtf(q * (1.f / DIM) + EPS);
    p[lane]       = g[lane] * d0 * inv + bta[lane];
    p[lane + 64]  = g[lane + 64] * d1 * inv + bta[lane + 64];
    p[lane + 128] = g[lane + 128] * d2 * inv + bta[lane + 128];
}

// ---------------- st = sum_p wA[p] * S3[b,p,:] ----------------
__global__ __launch_bounds__(DIM) void k_st(const float* __restrict__ wA, const float* __restrict__ S3,
                                            float* __restrict__ ST) {
    int b = blockIdx.x, d = threadIdx.x;
    __shared__ float w[LL];
    if (d < LL) w[d] = wA[d];
    __syncthreads();
    float s = 0.f;
    for (int p = 0; p < LL; ++p) s += w[p] * S3[((size_t)b * LL + p) * DIM + d];
    ST[b * DIM + d] = s;
}

// ---------------- GL = x_[b,L-1,:] @ wg2^T + wg2_b ----------------
__global__ __launch_bounds__(DIM) void k_gl(const float* __restrict__ X, const float* __restrict__ wg2W,
                                            const float* __restrict__ wg2b, float* __restrict__ GL) {
    int b = blockIdx.x, j = threadIdx.x;
    __shared__ float xr[DIM];
    xr[j] = X[((size_t)b * LL + LL - 1) * DIM + j];
    __syncthreads();
    float s = wg2b[j];
    const float* wr = wg2W + (size_t)j * DIM;
#pragma unroll 4
    for (int d = 0; d < DIM; ++d) s += xr[d] * wr[d];
    GL[b * DIM + j] = s;
}

// ---------------- ag = g @ gq ----------------
__global__ __launch_bounds__(256) void k_ag(const float* __restrict__ G, const float* __restrict__ gq,
                                            float* __restrict__ AG) {
    int r = blockIdx.x * 4 + (threadIdx.x >> 6);
    int lane = threadIdx.x & 63;
    const float* p = G + (size_t)r * DIM;
    float s = p[lane] * gq[lane] + p[lane + 64] * gq[lane + 64] + p[lane + 128] * gq[lane + 128];
#pragma unroll
    for (int off = 32; off; off >>= 1) s += __shfl_xor(s, off);
    if (lane == 0) AG[r] = s;
}

// ---------------- sg = sum_l ag[l] * x_[b,l,:] ----------------
__global__ __launch_bounds__(DIM) void k_sg(const float* __restrict__ AG, const float* __restrict__ X,
                                            float* __restrict__ SG) {
    int b = blockIdx.x, d = threadIdx.x;
    __shared__ float a[LL];
    if (d < LL) a[d] = AG[b * LL + d];
    __syncthreads();
    float s = 0.f;
    for (int l = 0; l < LL; ++l) s += a[l] * X[((size_t)b * LL + l) * DIM + d];
    SG[b * DIM + d] = s;
}

// ---------------- c = normalize(selu([st,sl,sg] @ wf^T + wf_b)) -> bf16 ----------------
__global__ __launch_bounds__(DIM) void k_c(const float* __restrict__ ST, const float* __restrict__ X,
                                           const float* __restrict__ SG, const float* __restrict__ wfW,
                                           const float* __restrict__ wfb, unsigned short* __restrict__ Cb16) {
    int b = blockIdx.x, t = threadIdx.x;
    __shared__ float v[3 * DIM];
    __shared__ float ssum[3];
    v[t]           = ST[b * DIM + t];
    v[DIM + t]     = X[((size_t)b * LL + LL - 1) * DIM + t];
    v[2 * DIM + t] = SG[b * DIM + t];
    __syncthreads();
    float cj = 0.f;
    if (t < IDIM) {
        float s = wfb[t];
        const float* wr = wfW + (size_t)t * (3 * DIM);
#pragma unroll 4
        for (int e = 0; e < 3 * DIM; ++e) s += v[e] * wr[e];
        const float sa = 1.6732632423543772f, sc = 1.0507009873554805f;
        cj = sc * (s > 0.f ? s : sa * expm1f(s));
    }
    float sq = cj * cj;
#pragma unroll
    for (int off = 32; off; off >>= 1) sq += __shfl_xor(sq, off);
    if ((t & 63) == 0) ssum[t >> 6] = sq;
    __syncthreads();
    if (t < IDIM) {
        float nrm = sqrtf(ssum[0] + ssum[1]);
        Cb16[b * IDIM + t] = f2bf(cj / nrm);
    }
}

// ---------------- Z: block = 64n strip x full 256m, LDS-transposed coalesced stores ----------------
__global__ __launch_bounds__(256) void k_z4(const unsigned short* __restrict__ Cb16,
                                            const unsigned short* __restrict__ emb16,
                                            const float* __restrict__ invn,
                                            float* __restrict__ Z) {
    __shared__ float tr[4][64][68];
    int n0 = blockIdx.x * 64;
    int t = threadIdx.x, w = t >> 6, l = t & 63;
    int lr = l & 15, lk = l >> 4;

    // A frags: wave w owns m-range [w*64, w*64+64): 4 m-tiles
    short8 a[4][4];
#pragma unroll
    for (int mt = 0; mt < 4; ++mt) {
        int mrow = w * 64 + mt * 16 + lr;
        const unsigned short* ap = Cb16 + (size_t)mrow * IDIM + lk * 8;
#pragma unroll
        for (int ks = 0; ks < 4; ++ks) a[mt][ks] = *(const short8*)(ap + ks * 32);
    }
    f32x4 acc[4][4] = {};
#pragma unroll
    for (int nt = 0; nt < 4; ++nt) {
        int nrow = n0 + nt * 16 + lr;
        short8 bfr[4];
        if (nrow < NOUT) {
            const unsigned short* bp = emb16 + (size_t)(nrow + 1) * IDIM + lk * 8;
#pragma unroll
            for (int ks = 0; ks < 4; ++ks) bfr[ks] = *(const short8*)(bp + ks * 32);
        } else {
            short8 z = {};
#pragma unroll
            for (int ks = 0; ks < 4; ++ks) bfr[ks] = z;
        }
#pragma unroll
        for (int mt = 0; mt < 4; ++mt)
#pragma unroll
            for (int ks = 0; ks < 4; ++ks)
                acc[mt][nt] = __builtin_amdgcn_mfma_f32_16x16x32_bf16(a[mt][ks], bfr[ks], acc[mt][nt], 0, 0, 0);
    }
    // stage (scaled) into LDS: [m-within-64][n-within-64]
#pragma unroll
    for (int nt = 0; nt < 4; ++nt) {
        int gn = n0 + nt * 16 + lr;
        float sc = (gn < NOUT) ? WSC * invn[gn + 1] : 0.f;
#pragma unroll
        for (int mt = 0; mt < 4; ++mt)
#pragma unroll
            for (int r = 0; r < 4; ++r)
                tr[w][mt * 16 + lk * 4 + r][nt * 16 + lr] = acc[mt][nt][r] * sc;
    }
    __syncthreads();
    // coalesced writes: quarter-wave per row, 16 lanes x float4 = 256B contiguous
    int q = l >> 4, s = l & 15;
    bool tail = (n0 + 64) > NOUT;
#pragma unroll
    for (int it = 0; it < 16; ++it) {
        int row = it * 4 + q;
        int gm  = w * 64 + row;
        float4 v = *(const float4*)&tr[w][row][s * 4];
        if (!tail) {
            *(float4*)&Z[(size_t)gm * NOUT + n0 + s * 4] = v;
        } else {
            int c0 = n0 + s * 4;
            float vv[4] = {v.x, v.y, v.z, v.w};
#pragma unroll
            for (int j = 0; j < 4; ++j)
                if (c0 + j < NOUT) Z[(size_t)gm * NOUT + c0 + j] = vv[j];
        }
    }
}

extern "C" void kernel_launch(void* const* d_in, const int* in_sizes, int n_in,
                              void* d_out, int out_size, void* d_ws, size_t ws_size,
                              hipStream_t stream) {
    const int*   x     = (const int*)d_in[0];
    const int*   pos   = (const int*)d_in[1];
    const float* emb   = (const float*)d_in[2];
    const float* pose  = (const float*)d_in[3];
    const float* vw0   = (const float*)d_in[4];
    const float* vw1   = (const float*)d_in[5];
    const float* vw2   = (const float*)d_in[6];
    const float* vbias = (const float*)d_in[7];
    const float* w1W   = (const float*)d_in[8];
    const float* w1b   = (const float*)d_in[9];
    const float* w2W   = (const float*)d_in[10];
    const float* w2b   = (const float*)d_in[11];
    const float* wA    = (const float*)d_in[12];
    const float* wg1W  = (const float*)d_in[13];
    const float* wg1b  = (const float*)d_in[14];
    const float* wg2W  = (const float*)d_in[15];
    const float* wg2b  = (const float*)d_in[16];
    const float* gq    = (const float*)d_in[17];
    const float* wfW   = (const float*)d_in[18];
    const float* wfb   = (const float*)d_in[19];
    const float* lng   = (const float*)d_in[20];
    const float* lnb   = (const float*)d_in[21];
    float* Z = (float*)d_out;

    float* w = (float*)d_ws;
    float* scale  = w; w += NITEMS;
    float* invn   = w; w += NITEMS;
    float* pscale = w; w += 64;
    float* X  = w; w += (size_t)BB * LL * DIM;
    float* Kb = w; w += (size_t)BB * LL * DIM;   // K' (vbias folded)
    float* Qb = w; w += (size_t)BB * LL * DIM;   // Q / S2 / S3
    float* Sb = w; w += (size_t)BB * LL * DIM;   // S / G
    float* Ab = w; w += (size_t)BB * LL * LL;
    float* AG = w; w += BB * LL;
    float* GL = w; w += BB * DIM;
    float* ST = w; w += BB * DIM;
    float* SG = w; w += BB * DIM;
    // bf16 scratch (16B aligned)
    w = (float*)(((uintptr_t)w + 15) & ~(uintptr_t)15);
    unsigned short* emb16 = (unsigned short*)w; w += (size_t)NITEMS * IDIM / 2;
    unsigned short* X16   = (unsigned short*)w; w += (size_t)BB * LL * DIM / 2;
    unsigned short* S16   = (unsigned short*)w; w += (size_t)BB * LL * DIM / 2;
    unsigned short* H16   = (unsigned short*)w; w += (size_t)BB * LL * DIM / 2;
    unsigned short* W16   = (unsigned short*)w; w += (size_t)5 * DIM * DIM / 2;
    unsigned short* Cb16  = (unsigned short*)w; w += (size_t)BB * IDIM / 2;
    unsigned short* vw1T16 = W16 + 0 * DIM * DIM;
    unsigned short* vw2T16 = W16 + 1 * DIM * DIM;
    unsigned short* w1W16  = W16 + 2 * DIM * DIM;
    unsigned short* w2W16  = W16 + 3 * DIM * DIM;
    unsigned short* wg1W16 = W16 + 4 * DIM * DIM;

    k_norms<<<NITEMS / 4, 256, 0, stream>>>(emb, scale, invn, emb16);
    k_pnorms<<<1, 64, 0, stream>>>(pose, pscale);
    k_cvtw<<<5 * 144, 256, 0, stream>>>(vw1, vw2, w1W, w2W, wg1W, W16);
    k_gather<<<BB, 256, 0, stream>>>(x, pos, emb, pose, scale, pscale, X, X16);
    k_gemm16<4><<<600, 256, 0, stream>>>(X16, vw1T16, vbias, nullptr, Kb);    // K' = X@vw1 + vbias
    k_gemm16<0><<<600, 256, 0, stream>>>(X16, vw2T16, nullptr, nullptr, Qb);  // Q  = X@vw2
    k_alpha2<<<BB * 2, 256, 0, stream>>>(Kb, Qb, x, vw0, Ab);
    k_attnS<<<BB, 256, 0, stream>>>(Ab, X, Sb, S16);
    k_gemm16<1><<<600, 256, 0, stream>>>(S16, w1W16, w1b, nullptr, H16);      // H2 (bf16)
    k_gemm16<2><<<600, 256, 0, stream>>>(H16, w2W16, w2b, Sb, Qb);            // S2
    k_ln<<<BB * LL, 64, 0, stream>>>(Qb, lng, lnb);                           // S3 in place
    k_st<<<BB, DIM, 0, stream>>>(wA, Qb, ST);
    k_gl<<<BB, DIM, 0, stream>>>(X, wg2W, wg2b, GL);
    k_gemm16<3><<<600, 256, 0, stream>>>(X16, wg1W16, wg1b, GL, Sb);          // G
    k_ag<<<BB * LL / 4, 256, 0, stream>>>(Sb, gq, AG);
    k_sg<<<BB, DIM, 0, stream>>>(AG, X, SG);
    k_c<<<BB, DIM, 0, stream>>>(ST, X, SG, wfW, wfb, Cb16);
    k_z4<<<(NOUT + 63) / 64, 256, 0, stream>>>(Cb16, emb16, invn, Z);
}

// Round 9
// 231.593 us; speedup vs baseline: 1.7021x; 1.0608x over previous
//
#include <hip/hip_runtime.h>
#include <hip/hip_bf16.h>
#include <math.h>
#include <stdint.h>

#define BB 256
#define LL 50
#define IDIM 128
#define PDIM 64
#define DIM 192
#define NITEMS 50000
#define NOUT 49999
#define WSC 20.0f
#define EPS 1e-5f

typedef __attribute__((ext_vector_type(8))) short  short8;
typedef __attribute__((ext_vector_type(4))) float  f32x4;

__device__ __forceinline__ unsigned short f2bf(float f) {
    unsigned int u = __float_as_uint(f);
    u = (u + 0x7FFFu + ((u >> 16) & 1u)) >> 16;
    return (unsigned short)u;
}

// ---------------- row norms of emb + bf16 copy ----------------
__global__ __launch_bounds__(256) void k_norms(const float* __restrict__ emb,
                                               float* __restrict__ scale,
                                               float* __restrict__ invn,
                                               unsigned short* __restrict__ emb16) {
    int row  = blockIdx.x * 4 + (threadIdx.x >> 6);
    int lane = threadIdx.x & 63;
    const float* p = emb + (size_t)row * IDIM;
    float a = p[lane], b = p[lane + 64];
    emb16[(size_t)row * IDIM + lane]      = f2bf(a);
    emb16[(size_t)row * IDIM + lane + 64] = f2bf(b);
    float s = a * a + b * b;
#pragma unroll
    for (int off = 32; off; off >>= 1) s += __shfl_xor(s, off);
    if (lane == 0) {
        float n = sqrtf(s);
        scale[row] = fminf(1.0f, 1.5f / fmaxf(n, 1e-7f));
        invn[row]  = (n > 0.f) ? 1.f / n : 0.f;
    }
}

__global__ __launch_bounds__(64) void k_pnorms(const float* __restrict__ pe,
                                               float* __restrict__ pscale) {
    int row = threadIdx.x;
    if (row > LL) return;
    float s = 0.f;
    const float* p = pe + row * PDIM;
    for (int d = 0; d < PDIM; ++d) { float v = p[d]; s += v * v; }
    float n = sqrtf(s);
    pscale[row] = fminf(1.0f, 1.5f / fmaxf(n, 1e-7f));
}

// ---------------- weight convert (+transpose for vw1,vw2) ----------------
__global__ __launch_bounds__(256) void k_cvtw(const float* __restrict__ vw1, const float* __restrict__ vw2,
                                              const float* __restrict__ w1W, const float* __restrict__ w2W,
                                              const float* __restrict__ wg1W,
                                              unsigned short* __restrict__ Wout) {
    int b = blockIdx.x;
    int wi = b / 144;
    int pos = (b % 144) * 256 + threadIdx.x;
    int n = pos / DIM, k = pos - n * DIM;
    float v;
    if      (wi == 0) v = vw1[(size_t)k * DIM + n];
    else if (wi == 1) v = vw2[(size_t)k * DIM + n];
    else if (wi == 2) v = w1W[pos];
    else if (wi == 3) v = w2W[pos];
    else              v = wg1W[pos];
    Wout[(size_t)wi * DIM * DIM + pos] = f2bf(v);
}

// ---------------- gather: X f32 + X bf16 ----------------
__global__ __launch_bounds__(256) void k_gather(const int* __restrict__ x, const int* __restrict__ pos,
                                                const float* __restrict__ emb, const float* __restrict__ pe,
                                                const float* __restrict__ scale, const float* __restrict__ pscale,
                                                float* __restrict__ X, unsigned short* __restrict__ X16) {
    int b = blockIdx.x, t = threadIdx.x;
    __shared__ int   xi[LL], pi[LL];
    __shared__ float xs[LL], ps[LL];
    if (t < LL) {
        int v = x[b * LL + t];  xi[t] = v;  xs[t] = scale[v];
        int pv = pos[b * LL + t]; pi[t] = pv; ps[t] = pscale[pv];
    }
    __syncthreads();
    for (int e = t; e < LL * DIM; e += 256) {
        int l = e / DIM, d = e - l * DIM;
        float v;
        if (d < IDIM) v = emb[(size_t)xi[l] * IDIM + d] * xs[l];
        else          v = pe[pi[l] * PDIM + (d - IDIM)] * ps[l];
        X[(size_t)b * LL * DIM + e]  = v;
        X16[(size_t)b * LL * DIM + e] = f2bf(v);
    }
}

// ---------------- bf16 MFMA GEMM ----------------
template <int MODE>
__global__ __launch_bounds__(256) void k_gemm16(const unsigned short* __restrict__ A16,
                                                const unsigned short* __restrict__ B16,
                                                const float* __restrict__ bias,
                                                const float* __restrict__ extra,
                                                void* __restrict__ Cout) {
    int mb = blockIdx.x % 200, nb = blockIdx.x / 200;
    int mbase = mb * 64, nbase = nb * 64;
    int t = threadIdx.x, w = t >> 6, l = t & 63;
    int lr = l & 15, lk = l >> 4;
    int arow = mbase + w * 16 + lr;
    const unsigned short* ap = A16 + (size_t)arow * DIM + lk * 8;
    short8 a[6];
#pragma unroll
    for (int ks = 0; ks < 6; ++ks) a[ks] = *(const short8*)(ap + ks * 32);
    f32x4 acc[4] = {};
#pragma unroll
    for (int nt = 0; nt < 4; ++nt) {
        int ncol = nbase + nt * 16 + lr;
        const unsigned short* bp = B16 + (size_t)ncol * DIM + lk * 8;
#pragma unroll
        for (int ks = 0; ks < 6; ++ks) {
            short8 bfr = *(const short8*)(bp + ks * 32);
            acc[nt] = __builtin_amdgcn_mfma_f32_16x16x32_bf16(a[ks], bfr, acc[nt], 0, 0, 0);
        }
    }
#pragma unroll
    for (int nt = 0; nt < 4; ++nt) {
        int gc = nbase + nt * 16 + lr;
        float bia = (MODE == 0) ? 0.f : bias[gc];
#pragma unroll
        for (int r = 0; r < 4; ++r) {
            int gr = mbase + w * 16 + lk * 4 + r;
            float v = acc[nt][r] + bia;
            if (MODE == 1)      v = fmaxf(v, 0.f);
            else if (MODE == 2) v += extra[(size_t)gr * DIM + gc];
            else if (MODE == 3) { v += extra[(size_t)(gr / LL) * DIM + gc]; v = 1.f / (1.f + expf(-v)); }
            if (MODE == 1) ((unsigned short*)Cout)[(size_t)gr * DIM + gc] = f2bf(v);
            else           ((float*)Cout)[(size_t)gr * DIM + gc] = v;
        }
    }
}

// ---------------- additive attention scores + masked softmax (v3) ----------------
// grid = BB*4; block owns <=13 i-rows. Wave w: d-slice [48w,48w+48).
// 4 independent accumulators break the FMA dependency chain.
__global__ __launch_bounds__(256) void k_alpha3(const float* __restrict__ Kp, const float* __restrict__ Qg,
                                                const int* __restrict__ x, const float* __restrict__ vw0,
                                                float* __restrict__ Ab) {
    int b    = blockIdx.x >> 2;
    int i0   = (blockIdx.x & 3) * 13;
    int cnt  = (i0 + 13 <= LL) ? 13 : (LL - i0);
    int t    = threadIdx.x;
    int wave = t >> 6, lane = t & 63;
    int d0   = wave * 48;

    __shared__ float Qs[13 * DIM];
    __shared__ float parts[4][13][64];
    __shared__ int   xs[64];

    const float4* Qbase = (const float4*)(Qg + ((size_t)b * LL + i0) * DIM);
    for (int e = t; e < cnt * (DIM / 4); e += 256) ((float4*)Qs)[e] = Qbase[e];
    if (t < 64) xs[t] = (t < LL) ? x[b * LL + t] : 0;

    float kr[48], wr[48];
    {
        const float* wp = vw0 + d0;
#pragma unroll
        for (int q = 0; q < 12; ++q) {
            float4 v = *(const float4*)(wp + q * 4);
            wr[q * 4] = v.x; wr[q * 4 + 1] = v.y; wr[q * 4 + 2] = v.z; wr[q * 4 + 3] = v.w;
        }
        if (lane < LL) {
            const float* kp = Kp + ((size_t)b * LL + lane) * DIM + d0;
#pragma unroll
            for (int q = 0; q < 12; ++q) {
                float4 v = *(const float4*)(kp + q * 4);
                kr[q * 4] = v.x; kr[q * 4 + 1] = v.y; kr[q * 4 + 2] = v.z; kr[q * 4 + 3] = v.w;
            }
        } else {
#pragma unroll
            for (int q = 0; q < 48; ++q) kr[q] = 0.f;
        }
    }
    __syncthreads();

    for (int i = 0; i < cnt; ++i) {
        const float* qrow = &Qs[i * DIM + d0];
        float a0 = 0.f, a1 = 0.f, a2 = 0.f, a3 = 0.f;
#pragma unroll
        for (int q = 0; q < 12; ++q) {
            float4 qv = *(const float4*)(qrow + q * 4);
            a0 += fmaxf(kr[q * 4 + 0] + qv.x, 0.f) * wr[q * 4 + 0];
            a1 += fmaxf(kr[q * 4 + 1] + qv.y, 0.f) * wr[q * 4 + 1];
            a2 += fmaxf(kr[q * 4 + 2] + qv.z, 0.f) * wr[q * 4 + 2];
            a3 += fmaxf(kr[q * 4 + 3] + qv.w, 0.f) * wr[q * 4 + 3];
        }
        parts[wave][i][lane] = (a0 + a1) + (a2 + a3);
    }
    __syncthreads();

    const float NEG = -__builtin_inff();
    bool valid = (lane < LL) && (xs[lane] != 0);
    for (int i = wave; i < cnt; i += 4) {
        float aj = parts[0][i][lane] + parts[1][i][lane] + parts[2][i][lane] + parts[3][i][lane];
        if (!valid) aj = NEG;
        float m = aj;
#pragma unroll
        for (int off = 32; off; off >>= 1) m = fmaxf(m, __shfl_xor(m, off));
        float e = valid ? expf(aj - m) : 0.f;
        float s = e;
#pragma unroll
        for (int off = 32; off; off >>= 1) s += __shfl_xor(s, off);
        if (lane < LL) Ab[((size_t)b * LL + i0 + i) * LL + lane] = e / s;
    }
}

// ---------------- S = a @ x_  (f32 + bf16 out) ----------------
__global__ __launch_bounds__(256) void k_attnS(const float* __restrict__ Ab, const float* __restrict__ X,
                                               float* __restrict__ Sb, unsigned short* __restrict__ S16) {
    int b = blockIdx.x, t = threadIdx.x;
    __shared__ float As[LL][LL];
    __shared__ float Xs[LL][DIM];
    for (int e = t; e < LL * LL; e += 256) As[e / LL][e % LL] = Ab[(size_t)b * LL * LL + e];
    for (int e = t; e < LL * DIM; e += 256) Xs[e / DIM][e % DIM] = X[(size_t)b * LL * DIM + e];
    __syncthreads();
    for (int o = t; o < LL * DIM; o += 256) {
        int i = o / DIM, d = o - i * DIM;
        float s = 0.f;
#pragma unroll 5
        for (int j = 0; j < LL; ++j) s += As[i][j] * Xs[j][d];
        Sb[(size_t)b * LL * DIM + o]  = s;
        S16[(size_t)b * LL * DIM + o] = f2bf(s);
    }
}

// ---------------- LayerNorm (in place), 4 rows/block ----------------
__global__ __launch_bounds__(256) void k_ln(float* __restrict__ S2, const float* __restrict__ g,
                                            const float* __restrict__ bta) {
    size_t row = (size_t)blockIdx.x * 4 + (threadIdx.x >> 6);
    float* p = S2 + row * DIM;
    int lane = threadIdx.x & 63;
    float v0 = p[lane], v1 = p[lane + 64], v2 = p[lane + 128];
    float s = v0 + v1 + v2;
#pragma unroll
    for (int off = 32; off; off >>= 1) s += __shfl_xor(s, off);
    float mu = s * (1.f / DIM);
    float d0 = v0 - mu, d1 = v1 - mu, d2 = v2 - mu;
    float q = d0 * d0 + d1 * d1 + d2 * d2;
#pragma unroll
    for (int off = 32; off; off >>= 1) q += __shfl_xor(q, off);
    float inv = rsqrtf(q * (1.f / DIM) + EPS);
    p[lane]       = g[lane] * d0 * inv + bta[lane];
    p[lane + 64]  = g[lane + 64] * d1 * inv + bta[lane + 64];
    p[lane + 128] = g[lane + 128] * d2 * inv + bta[lane + 128];
}

// ---------------- fused: ST = wA@S3  and  GL = x_last@wg2^T + b ----------------
__global__ __launch_bounds__(DIM) void k_stgl(const float* __restrict__ wA, const float* __restrict__ S3,
                                              const float* __restrict__ X, const float* __restrict__ wg2W,
                                              const float* __restrict__ wg2b,
                                              float* __restrict__ ST, float* __restrict__ GL) {
    int b = blockIdx.x, d = threadIdx.x;
    __shared__ float w[LL];
    __shared__ float xr[DIM];
    if (d < LL) w[d] = wA[d];
    xr[d] = X[((size_t)b * LL + LL - 1) * DIM + d];
    __syncthreads();
    float s = 0.f;
    for (int p = 0; p < LL; ++p) s += w[p] * S3[((size_t)b * LL + p) * DIM + d];
    ST[b * DIM + d] = s;
    float g = wg2b[d];
    const float* wr = wg2W + (size_t)d * DIM;
#pragma unroll 4
    for (int k = 0; k < DIM; ++k) g += xr[k] * wr[k];
    GL[b * DIM + d] = g;
}

// ---------------- fused: ag = G@gq ; sg = ag @ x_ ----------------
__global__ __launch_bounds__(256) void k_agsg(const float* __restrict__ G, const float* __restrict__ gq,
                                              const float* __restrict__ X, float* __restrict__ SG) {
    int b = blockIdx.x, t = threadIdx.x;
    int wave = t >> 6, lane = t & 63;
    __shared__ float ags[LL];
    __shared__ float gqs[DIM];
    if (t < DIM) gqs[t] = gq[t];
    __syncthreads();
    for (int r = wave; r < LL; r += 4) {
        const float* p = G + ((size_t)b * LL + r) * DIM;
        float s = p[lane] * gqs[lane] + p[lane + 64] * gqs[lane + 64] + p[lane + 128] * gqs[lane + 128];
#pragma unroll
        for (int off = 32; off; off >>= 1) s += __shfl_xor(s, off);
        if (lane == 0) ags[r] = s;
    }
    __syncthreads();
    if (t < DIM) {
        float s = 0.f;
        for (int l = 0; l < LL; ++l) s += ags[l] * X[((size_t)b * LL + l) * DIM + t];
        SG[b * DIM + t] = s;
    }
}

// ---------------- c = normalize(selu([st,sl,sg] @ wf^T + wf_b)) -> bf16 ----------------
__global__ __launch_bounds__(DIM) void k_c(const float* __restrict__ ST, const float* __restrict__ X,
                                           const float* __restrict__ SG, const float* __restrict__ wfW,
                                           const float* __restrict__ wfb, unsigned short* __restrict__ Cb16) {
    int b = blockIdx.x, t = threadIdx.x;
    __shared__ float v[3 * DIM];
    __shared__ float ssum[3];
    v[t]           = ST[b * DIM + t];
    v[DIM + t]     = X[((size_t)b * LL + LL - 1) * DIM + t];
    v[2 * DIM + t] = SG[b * DIM + t];
    __syncthreads();
    float cj = 0.f;
    if (t < IDIM) {
        float s = wfb[t];
        const float* wr = wfW + (size_t)t * (3 * DIM);
#pragma unroll 4
        for (int e = 0; e < 3 * DIM; ++e) s += v[e] * wr[e];
        const float sa = 1.6732632423543772f, sc = 1.0507009873554805f;
        cj = sc * (s > 0.f ? s : sa * expm1f(s));
    }
    float sq = cj * cj;
#pragma unroll
    for (int off = 32; off; off >>= 1) sq += __shfl_xor(sq, off);
    if ((t & 63) == 0) ssum[t >> 6] = sq;
    __syncthreads();
    if (t < IDIM) {
        float nrm = sqrtf(ssum[0] + ssum[1]);
        Cb16[b * IDIM + t] = f2bf(cj / nrm);
    }
}

// ---------------- Z: block = 64n strip x full 256m, LDS-transposed coalesced stores ----------------
__global__ __launch_bounds__(256) void k_z4(const unsigned short* __restrict__ Cb16,
                                            const unsigned short* __restrict__ emb16,
                                            const float* __restrict__ invn,
                                            float* __restrict__ Z) {
    __shared__ float tr[4][64][68];
    int n0 = blockIdx.x * 64;
    int t = threadIdx.x, w = t >> 6, l = t & 63;
    int lr = l & 15, lk = l >> 4;

    short8 a[4][4];
#pragma unroll
    for (int mt = 0; mt < 4; ++mt) {
        int mrow = w * 64 + mt * 16 + lr;
        const unsigned short* ap = Cb16 + (size_t)mrow * IDIM + lk * 8;
#pragma unroll
        for (int ks = 0; ks < 4; ++ks) a[mt][ks] = *(const short8*)(ap + ks * 32);
    }
    f32x4 acc[4][4] = {};
#pragma unroll
    for (int nt = 0; nt < 4; ++nt) {
        int nrow = n0 + nt * 16 + lr;
        short8 bfr[4];
        if (nrow < NOUT) {
            const unsigned short* bp = emb16 + (size_t)(nrow + 1) * IDIM + lk * 8;
#pragma unroll
            for (int ks = 0; ks < 4; ++ks) bfr[ks] = *(const short8*)(bp + ks * 32);
        } else {
            short8 z = {};
#pragma unroll
            for (int ks = 0; ks < 4; ++ks) bfr[ks] = z;
        }
#pragma unroll
        for (int mt = 0; mt < 4; ++mt)
#pragma unroll
            for (int ks = 0; ks < 4; ++ks)
                acc[mt][nt] = __builtin_amdgcn_mfma_f32_16x16x32_bf16(a[mt][ks], bfr[ks], acc[mt][nt], 0, 0, 0);
    }
#pragma unroll
    for (int nt = 0; nt < 4; ++nt) {
        int gn = n0 + nt * 16 + lr;
        float sc = (gn < NOUT) ? WSC * invn[gn + 1] : 0.f;
#pragma unroll
        for (int mt = 0; mt < 4; ++mt)
#pragma unroll
            for (int r = 0; r < 4; ++r)
                tr[w][mt * 16 + lk * 4 + r][nt * 16 + lr] = acc[mt][nt][r] * sc;
    }
    __syncthreads();
    int q = l >> 4, s = l & 15;
    bool tail = (n0 + 64) > NOUT;
#pragma unroll
    for (int it = 0; it < 16; ++it) {
        int row = it * 4 + q;
        int gm  = w * 64 + row;
        float4 v = *(const float4*)&tr[w][row][s * 4];
        if (!tail) {
            *(float4*)&Z[(size_t)gm * NOUT + n0 + s * 4] = v;
        } else {
            int c0 = n0 + s * 4;
            float vv[4] = {v.x, v.y, v.z, v.w};
#pragma unroll
            for (int j = 0; j < 4; ++j)
                if (c0 + j < NOUT) Z[(size_t)gm * NOUT + c0 + j] = vv[j];
        }
    }
}

extern "C" void kernel_launch(void* const* d_in, const int* in_sizes, int n_in,
                              void* d_out, int out_size, void* d_ws, size_t ws_size,
                              hipStream_t stream) {
    const int*   x     = (const int*)d_in[0];
    const int*   pos   = (const int*)d_in[1];
    const float* emb   = (const float*)d_in[2];
    const float* pose  = (const float*)d_in[3];
    const float* vw0   = (const float*)d_in[4];
    const float* vw1   = (const float*)d_in[5];
    const float* vw2   = (const float*)d_in[6];
    const float* vbias = (const float*)d_in[7];
    const float* w1W   = (const float*)d_in[8];
    const float* w1b   = (const float*)d_in[9];
    const float* w2W   = (const float*)d_in[10];
    const float* w2b   = (const float*)d_in[11];
    const float* wA    = (const float*)d_in[12];
    const float* wg1W  = (const float*)d_in[13];
    const float* wg1b  = (const float*)d_in[14];
    const float* wg2W  = (const float*)d_in[15];
    const float* wg2b  = (const float*)d_in[16];
    const float* gq    = (const float*)d_in[17];
    const float* wfW   = (const float*)d_in[18];
    const float* wfb   = (const float*)d_in[19];
    const float* lng   = (const float*)d_in[20];
    const float* lnb   = (const float*)d_in[21];
    float* Z = (float*)d_out;

    float* w = (float*)d_ws;
    float* scale  = w; w += NITEMS;
    float* invn   = w; w += NITEMS;
    float* pscale = w; w += 64;
    float* X  = w; w += (size_t)BB * LL * DIM;
    float* Kb = w; w += (size_t)BB * LL * DIM;   // K' (vbias folded)
    float* Qb = w; w += (size_t)BB * LL * DIM;   // Q / S2 / S3
    float* Sb = w; w += (size_t)BB * LL * DIM;   // S / G
    float* Ab = w; w += (size_t)BB * LL * LL;
    float* GL = w; w += BB * DIM;
    float* ST = w; w += BB * DIM;
    float* SG = w; w += BB * DIM;
    // bf16 scratch (16B aligned)
    w = (float*)(((uintptr_t)w + 15) & ~(uintptr_t)15);
    unsigned short* emb16 = (unsigned short*)w; w += (size_t)NITEMS * IDIM / 2;
    unsigned short* X16   = (unsigned short*)w; w += (size_t)BB * LL * DIM / 2;
    unsigned short* S16   = (unsigned short*)w; w += (size_t)BB * LL * DIM / 2;
    unsigned short* H16   = (unsigned short*)w; w += (size_t)BB * LL * DIM / 2;
    unsigned short* W16   = (unsigned short*)w; w += (size_t)5 * DIM * DIM / 2;
    unsigned short* Cb16  = (unsigned short*)w; w += (size_t)BB * IDIM / 2;
    unsigned short* vw1T16 = W16 + 0 * DIM * DIM;
    unsigned short* vw2T16 = W16 + 1 * DIM * DIM;
    unsigned short* w1W16  = W16 + 2 * DIM * DIM;
    unsigned short* w2W16  = W16 + 3 * DIM * DIM;
    unsigned short* wg1W16 = W16 + 4 * DIM * DIM;

    k_norms<<<NITEMS / 4, 256, 0, stream>>>(emb, scale, invn, emb16);
    k_pnorms<<<1, 64, 0, stream>>>(pose, pscale);
    k_cvtw<<<5 * 144, 256, 0, stream>>>(vw1, vw2, w1W, w2W, wg1W, W16);
    k_gather<<<BB, 256, 0, stream>>>(x, pos, emb, pose, scale, pscale, X, X16);
    k_gemm16<4><<<600, 256, 0, stream>>>(X16, vw1T16, vbias, nullptr, Kb);    // K' = X@vw1 + vbias
    k_gemm16<0><<<600, 256, 0, stream>>>(X16, vw2T16, nullptr, nullptr, Qb);  // Q  = X@vw2
    k_alpha3<<<BB * 4, 256, 0, stream>>>(Kb, Qb, x, vw0, Ab);
    k_attnS<<<BB, 256, 0, stream>>>(Ab, X, Sb, S16);
    k_gemm16<1><<<600, 256, 0, stream>>>(S16, w1W16, w1b, nullptr, H16);      // H2 (bf16)
    k_gemm16<2><<<600, 256, 0, stream>>>(H16, w2W16, w2b, Sb, Qb);            // S2
    k_ln<<<BB * LL / 4, 256, 0, stream>>>(Qb, lng, lnb);                      // S3 in place
    k_stgl<<<BB, DIM, 0, stream>>>(wA, Qb, X, wg2W, wg2b, ST, GL);
    k_gemm16<3><<<600, 256, 0, stream>>>(X16, wg1W16, wg1b, GL, Sb);          // G
    k_agsg<<<BB, 256, 0, stream>>>(Sb, gq, X, SG);
    k_c<<<BB, DIM, 0, stream>>>(ST, X, SG, wfW, wfb, Cb16);
    k_z4<<<(NOUT + 63) / 64, 256, 0, stream>>>(Cb16, emb16, invn, Z);
}

// Round 10
// 124.672 us; speedup vs baseline: 3.1618x; 1.8576x over previous
//
#include <hip/hip_runtime.h>
#include <hip/hip_bf16.h>
#include <math.h>
#include <stdint.h>

#define BB 256
#define LL 50
#define IDIM 128
#define PDIM 64
#define DIM 192
#define NITEMS 50000
#define NOUT 49999
#define WSC 20.0f
#define EPS 1e-5f
#define WMAT (DIM * DIM)

typedef __attribute__((ext_vector_type(8))) short  short8;
typedef __attribute__((ext_vector_type(4))) float  f32x4;

__device__ __forceinline__ unsigned short f2bf(float f) {
    unsigned int u = __float_as_uint(f);
    u = (u + 0x7FFFu + ((u >> 16) & 1u)) >> 16;
    return (unsigned short)u;
}

// ---------------- row norms of emb + bf16 copy ----------------
__global__ __launch_bounds__(256) void k_norms(const float* __restrict__ emb,
                                               float* __restrict__ scale,
                                               float* __restrict__ invn,
                                               unsigned short* __restrict__ emb16) {
    int row  = blockIdx.x * 4 + (threadIdx.x >> 6);
    int lane = threadIdx.x & 63;
    const float* p = emb + (size_t)row * IDIM;
    float a = p[lane], b = p[lane + 64];
    emb16[(size_t)row * IDIM + lane]      = f2bf(a);
    emb16[(size_t)row * IDIM + lane + 64] = f2bf(b);
    float s = a * a + b * b;
#pragma unroll
    for (int off = 32; off; off >>= 1) s += __shfl_xor(s, off);
    if (lane == 0) {
        float n = sqrtf(s);
        scale[row] = fminf(1.0f, 1.5f / fmaxf(n, 1e-7f));
        invn[row]  = (n > 0.f) ? 1.f / n : 0.f;
    }
}

__global__ __launch_bounds__(64) void k_pnorms(const float* __restrict__ pe,
                                               float* __restrict__ pscale) {
    int row = threadIdx.x;
    if (row > LL) return;
    float s = 0.f;
    const float* p = pe + row * PDIM;
    for (int d = 0; d < PDIM; ++d) { float v = p[d]; s += v * v; }
    float n = sqrtf(s);
    pscale[row] = fminf(1.0f, 1.5f / fmaxf(n, 1e-7f));
}

// ---------------- weight convert (+transpose for vw1,vw2) ----------------
// W16 layout: [0]=vw1^T [1]=vw2^T [2]=w1W [3]=w2W [4]=wg1W, each [n][k] 192x192
__global__ __launch_bounds__(256) void k_cvtw(const float* __restrict__ vw1, const float* __restrict__ vw2,
                                              const float* __restrict__ w1W, const float* __restrict__ w2W,
                                              const float* __restrict__ wg1W,
                                              unsigned short* __restrict__ Wout) {
    int b = blockIdx.x;
    int wi = b / 144;
    int pos = (b % 144) * 256 + threadIdx.x;
    int n = pos / DIM, k = pos - n * DIM;
    float v;
    if      (wi == 0) v = vw1[(size_t)k * DIM + n];
    else if (wi == 1) v = vw2[(size_t)k * DIM + n];
    else if (wi == 2) v = w1W[pos];
    else if (wi == 3) v = w2W[pos];
    else              v = wg1W[pos];
    Wout[(size_t)wi * WMAT + pos] = f2bf(v);
}

// ================= MEGAKERNEL: whole per-batch chain =================
// block b: gather -> GL -> {K',Q,Gpre}MFMA -> alpha -> S -> H2 -> S2 -> LN -> ST/SG -> c
__global__ __launch_bounds__(512) void k_mega(
    const int* __restrict__ x, const int* __restrict__ pos,
    const float* __restrict__ emb, const float* __restrict__ pe,
    const float* __restrict__ scale, const float* __restrict__ pscale,
    const unsigned short* __restrict__ W16,
    const float* __restrict__ vw0, const float* __restrict__ vbias,
    const float* __restrict__ w1b, const float* __restrict__ w2b,
    const float* __restrict__ wg1b, const float* __restrict__ wg2W,
    const float* __restrict__ wg2b, const float* __restrict__ gq,
    const float* __restrict__ wA, const float* __restrict__ lng,
    const float* __restrict__ lnb, const float* __restrict__ wfW,
    const float* __restrict__ wfb, unsigned short* __restrict__ Cb16g) {

    __shared__ float Xs[LL * DIM];                 // 38400 B, f32 X (lives whole kernel)
    __shared__ unsigned short Bs16[64 * DIM];      // 24576 B, swizzled: X16 -> S16 -> H16
    __shared__ float R1[LL * 196];                 // 39200 B: K' -> parts[8][12][64]+Ab[50][64]
    __shared__ float R2[LL * 196];                 // 39200 B: Q -> S -> S2/S3
    __shared__ float GLs[DIM];
    __shared__ float cvec[3 * DIM];
    __shared__ float ags[64];
    __shared__ int   msk[64];
    __shared__ float was[64];
    __shared__ float red[8];
    __shared__ int   xi[LL], pii[LL];
    __shared__ float xsc[LL], psc[LL];

    const int b = blockIdx.x, t = threadIdx.x;
    const int wv = t >> 6, l = t & 63;
    const int lr = l & 15, lk = l >> 4;

    // ---- P0: indices, consts, gather X (f32) + swizzled bf16, zero tail ----
    if (t < LL) {
        int v = x[b * LL + t];  xi[t] = v;  xsc[t] = scale[v];
        int pv = pos[b * LL + t]; pii[t] = pv; psc[t] = pscale[pv];
    }
    if (t >= 64 && t < 128) ags[t - 64] = 0.f;
    if (t >= 128 && t < 128 + LL) was[t - 128] = wA[t - 128];
    __syncthreads();
    if (t < 64) msk[t] = (t < LL) ? xi[t] : 0;
    for (int e = t; e < LL * DIM; e += 512) {
        int r = e / DIM, d = e - r * DIM;
        float v;
        if (d < IDIM) v = emb[(size_t)xi[r] * IDIM + d] * xsc[r];
        else          v = pe[pii[r] * PDIM + (d - IDIM)] * psc[r];
        Xs[e] = v;
        int byte = r * 384 + d * 2; byte ^= (r & 7) << 4;
        *(unsigned short*)((char*)Bs16 + byte) = f2bf(v);
    }
    for (int e = t; e < 14 * DIM; e += 512) Bs16[LL * DIM + ((50 * DIM - LL * DIM) ? 0 : 0) + e] = 0;  // rows 50..63
    __syncthreads();

    // ---- P0.5: GL = X[49] @ wg2W^T + wg2b ----
    if (t < DIM) {
        float g = wg2b[t];
        const float* wr = wg2W + (size_t)t * DIM;
        float s0 = 0, s1 = 0, s2 = 0, s3 = 0;
        const float* xr = &Xs[49 * DIM];
        for (int k = 0; k < DIM; k += 4) {
            float4 w4 = *(const float4*)(wr + k);
            s0 += xr[k] * w4.x; s1 += xr[k + 1] * w4.y; s2 += xr[k + 2] * w4.z; s3 += xr[k + 3] * w4.w;
        }
        GLs[t] = g + ((s0 + s1) + (s2 + s3));
    }
    __syncthreads();

    // ---- P1: three GEMMs sharing A = X16 (swizzled LDS): K'->R1, Q->R2, Gpre->ags ----
    {
        short8 afr[4][6];
#pragma unroll
        for (int mt = 0; mt < 4; ++mt) {
            int row = mt * 16 + lr;
#pragma unroll
            for (int ks = 0; ks < 6; ++ks) {
                int byte = row * 384 + (lk * 8 + ks * 32) * 2; byte ^= (row & 7) << 4;
                afr[mt][ks] = *(const short8*)((const char*)Bs16 + byte);
            }
        }
        for (int task = wv; task < 36; task += 8) {
            int out = task / 12, nt = task % 12;
            int ncol = nt * 16 + lr;
            const unsigned short* bp = W16 + (size_t)(out == 0 ? 0 : (out == 1 ? 1 : 4)) * WMAT
                                       + (size_t)ncol * DIM + lk * 8;
            f32x4 a0 = {}, a1 = {}, a2 = {}, a3 = {};
#pragma unroll
            for (int ks = 0; ks < 6; ++ks) {
                short8 bf = *(const short8*)(bp + ks * 32);
                a0 = __builtin_amdgcn_mfma_f32_16x16x32_bf16(afr[0][ks], bf, a0, 0, 0, 0);
                a1 = __builtin_amdgcn_mfma_f32_16x16x32_bf16(afr[1][ks], bf, a1, 0, 0, 0);
                a2 = __builtin_amdgcn_mfma_f32_16x16x32_bf16(afr[2][ks], bf, a2, 0, 0, 0);
                a3 = __builtin_amdgcn_mfma_f32_16x16x32_bf16(afr[3][ks], bf, a3, 0, 0, 0);
            }
            if (out == 0) {
                float bia = vbias[ncol];
#pragma unroll
                for (int mt = 0; mt < 4; ++mt) {
                    f32x4 ac = (mt == 0) ? a0 : (mt == 1) ? a1 : (mt == 2) ? a2 : a3;
#pragma unroll
                    for (int r = 0; r < 4; ++r) {
                        int gr = mt * 16 + lk * 4 + r;
                        if (gr < LL) R1[gr * 196 + ncol] = ac[r] + bia;
                    }
                }
            } else if (out == 1) {
#pragma unroll
                for (int mt = 0; mt < 4; ++mt) {
                    f32x4 ac = (mt == 0) ? a0 : (mt == 1) ? a1 : (mt == 2) ? a2 : a3;
#pragma unroll
                    for (int r = 0; r < 4; ++r) {
                        int gr = mt * 16 + lk * 4 + r;
                        if (gr < LL) R2[gr * 196 + ncol] = ac[r];
                    }
                }
            } else {
                float bia = wg1b[ncol] + GLs[ncol];
                float gqv = gq[ncol];
#pragma unroll
                for (int mt = 0; mt < 4; ++mt) {
                    f32x4 ac = (mt == 0) ? a0 : (mt == 1) ? a1 : (mt == 2) ? a2 : a3;
                    float c0, c1, c2, c3;
                    {
                        int gr0 = mt * 16 + lk * 4;
                        float v0 = ac[0] + bia, v1 = ac[1] + bia, v2 = ac[2] + bia, v3 = ac[3] + bia;
                        c0 = (gr0 + 0 < LL) ? gqv / (1.f + expf(-v0)) : 0.f;
                        c1 = (gr0 + 1 < LL) ? gqv / (1.f + expf(-v1)) : 0.f;
                        c2 = (gr0 + 2 < LL) ? gqv / (1.f + expf(-v2)) : 0.f;
                        c3 = (gr0 + 3 < LL) ? gqv / (1.f + expf(-v3)) : 0.f;
                    }
#pragma unroll
                    for (int off = 1; off < 16; off <<= 1) {
                        c0 += __shfl_xor(c0, off); c1 += __shfl_xor(c1, off);
                        c2 += __shfl_xor(c2, off); c3 += __shfl_xor(c3, off);
                    }
                    if (lr == 0) {
                        int gr0 = mt * 16 + lk * 4;
                        if (gr0 + 0 < LL) atomicAdd(&ags[gr0 + 0], c0);
                        if (gr0 + 1 < LL) atomicAdd(&ags[gr0 + 1], c1);
                        if (gr0 + 2 < LL) atomicAdd(&ags[gr0 + 2], c2);
                        if (gr0 + 3 < LL) atomicAdd(&ags[gr0 + 3], c3);
                    }
                }
            }
        }
    }
    __syncthreads();   // K', Q, ags complete

    // ---- P2: alpha + masked softmax -> Ab (in R1 region) ----
    {
        const int d0 = wv * 24;
        float kr[24], wr[24];
        {
            const float* wp = vw0 + d0;
#pragma unroll
            for (int q = 0; q < 6; ++q) {
                float4 v = *(const float4*)(wp + q * 4);
                wr[q * 4] = v.x; wr[q * 4 + 1] = v.y; wr[q * 4 + 2] = v.z; wr[q * 4 + 3] = v.w;
            }
            if (l < LL) {
                const float* kp = R1 + l * 196 + d0;
#pragma unroll
                for (int q = 0; q < 6; ++q) {
                    float4 v = *(const float4*)(kp + q * 4);
                    kr[q * 4] = v.x; kr[q * 4 + 1] = v.y; kr[q * 4 + 2] = v.z; kr[q * 4 + 3] = v.w;
                }
            } else {
#pragma unroll
                for (int q = 0; q < 24; ++q) kr[q] = 0.f;
            }
        }
        __syncthreads();   // kr cached; R1 free
        float* parts = R1;              // [8][12][64] = 6144 floats
        float* Ab    = R1 + 6144;       // [50][64]   = 3200 floats
        const float NEG = -__builtin_inff();
        bool valid = (l < LL) && (msk[l] != 0);
        for (int i0 = 0; i0 < LL; i0 += 12) {
            int cnt = (i0 + 12 <= LL) ? 12 : (LL - i0);
            for (int i = 0; i < cnt; ++i) {
                const float* qrow = R2 + (i0 + i) * 196 + d0;
                float b0 = 0, b1 = 0, b2 = 0, b3 = 0;
#pragma unroll
                for (int q = 0; q < 6; ++q) {
                    float4 qv = *(const float4*)(qrow + q * 4);
                    b0 += fmaxf(kr[q * 4 + 0] + qv.x, 0.f) * wr[q * 4 + 0];
                    b1 += fmaxf(kr[q * 4 + 1] + qv.y, 0.f) * wr[q * 4 + 1];
                    b2 += fmaxf(kr[q * 4 + 2] + qv.z, 0.f) * wr[q * 4 + 2];
                    b3 += fmaxf(kr[q * 4 + 3] + qv.w, 0.f) * wr[q * 4 + 3];
                }
                parts[(wv * 12 + i) * 64 + l] = (b0 + b1) + (b2 + b3);
            }
            __syncthreads();
            for (int i = wv; i < cnt; i += 8) {
                float aj = 0.f;
#pragma unroll
                for (int w2 = 0; w2 < 8; ++w2) aj += parts[(w2 * 12 + i) * 64 + l];
                if (!valid) aj = NEG;
                float m = aj;
#pragma unroll
                for (int off = 32; off; off >>= 1) m = fmaxf(m, __shfl_xor(m, off));
                float e = valid ? expf(aj - m) : 0.f;
                float s = e;
#pragma unroll
                for (int off = 32; off; off >>= 1) s += __shfl_xor(s, off);
                Ab[(i0 + i) * 64 + l] = e / s;
            }
            __syncthreads();
        }
    }

    // ---- P3: S = Ab @ Xs -> R2 (f32) + Bs16 (bf16 swizzled) ----
    {
        const float* Ab = R1 + 6144;
        for (int o = t; o < LL * DIM; o += 512) {
            int i = o / DIM, d = o - i * DIM;
            float s = 0.f;
#pragma unroll
            for (int q = 0; q < 12; ++q) {
                float4 av = *(const float4*)(Ab + i * 64 + q * 4);
                s += av.x * Xs[(q * 4 + 0) * DIM + d] + av.y * Xs[(q * 4 + 1) * DIM + d]
                   + av.z * Xs[(q * 4 + 2) * DIM + d] + av.w * Xs[(q * 4 + 3) * DIM + d];
            }
            s += Ab[i * 64 + 48] * Xs[48 * DIM + d] + Ab[i * 64 + 49] * Xs[49 * DIM + d];
            R2[i * 196 + d] = s;
            int byte = i * 384 + d * 2; byte ^= (i & 7) << 4;
            *(unsigned short*)((char*)Bs16 + byte) = f2bf(s);
        }
    }
    __syncthreads();

    // ---- P4: H2 = relu(S@w1 + b) : acc in regs, barrier, write bf16 back into Bs16 ----
    {
        short8 sfr[4][6];
#pragma unroll
        for (int mt = 0; mt < 4; ++mt) {
            int row = mt * 16 + lr;
#pragma unroll
            for (int ks = 0; ks < 6; ++ks) {
                int byte = row * 384 + (lk * 8 + ks * 32) * 2; byte ^= (row & 7) << 4;
                sfr[mt][ks] = *(const short8*)((const char*)Bs16 + byte);
            }
        }
        f32x4 h0[4] = {}, h1[4] = {};
        {
            int ncol = wv * 16 + lr;
            const unsigned short* bp = W16 + (size_t)2 * WMAT + (size_t)ncol * DIM + lk * 8;
#pragma unroll
            for (int ks = 0; ks < 6; ++ks) {
                short8 bf = *(const short8*)(bp + ks * 32);
                h0[0] = __builtin_amdgcn_mfma_f32_16x16x32_bf16(sfr[0][ks], bf, h0[0], 0, 0, 0);
                h0[1] = __builtin_amdgcn_mfma_f32_16x16x32_bf16(sfr[1][ks], bf, h0[1], 0, 0, 0);
                h0[2] = __builtin_amdgcn_mfma_f32_16x16x32_bf16(sfr[2][ks], bf, h0[2], 0, 0, 0);
                h0[3] = __builtin_amdgcn_mfma_f32_16x16x32_bf16(sfr[3][ks], bf, h0[3], 0, 0, 0);
            }
        }
        if (wv < 4) {
            int ncol = (wv + 8) * 16 + lr;
            const unsigned short* bp = W16 + (size_t)2 * WMAT + (size_t)ncol * DIM + lk * 8;
#pragma unroll
            for (int ks = 0; ks < 6; ++ks) {
                short8 bf = *(const short8*)(bp + ks * 32);
                h1[0] = __builtin_amdgcn_mfma_f32_16x16x32_bf16(sfr[0][ks], bf, h1[0], 0, 0, 0);
                h1[1] = __builtin_amdgcn_mfma_f32_16x16x32_bf16(sfr[1][ks], bf, h1[1], 0, 0, 0);
                h1[2] = __builtin_amdgcn_mfma_f32_16x16x32_bf16(sfr[2][ks], bf, h1[2], 0, 0, 0);
                h1[3] = __builtin_amdgcn_mfma_f32_16x16x32_bf16(sfr[3][ks], bf, h1[3], 0, 0, 0);
            }
        }
        __syncthreads();   // all S16 reads done
        {
            int gc = wv * 16 + lr;
            float bia = w1b[gc];
#pragma unroll
            for (int mt = 0; mt < 4; ++mt)
#pragma unroll
                for (int r = 0; r < 4; ++r) {
                    int gr = mt * 16 + lk * 4 + r;
                    if (gr < LL) {
                        float v = fmaxf(h0[mt][r] + bia, 0.f);
                        int byte = gr * 384 + gc * 2; byte ^= (gr & 7) << 4;
                        *(unsigned short*)((char*)Bs16 + byte) = f2bf(v);
                    }
                }
        }
        if (wv < 4) {
            int gc = (wv + 8) * 16 + lr;
            float bia = w1b[gc];
#pragma unroll
            for (int mt = 0; mt < 4; ++mt)
#pragma unroll
                for (int r = 0; r < 4; ++r) {
                    int gr = mt * 16 + lk * 4 + r;
                    if (gr < LL) {
                        float v = fmaxf(h1[mt][r] + bia, 0.f);
                        int byte = gr * 384 + gc * 2; byte ^= (gr & 7) << 4;
                        *(unsigned short*)((char*)Bs16 + byte) = f2bf(v);
                    }
                }
        }
    }
    __syncthreads();

    // ---- P5: S2 = H2@w2 + b + S (residual in-place in R2) ----
    {
        short8 hfr[4][6];
#pragma unroll
        for (int mt = 0; mt < 4; ++mt) {
            int row = mt * 16 + lr;
#pragma unroll
            for (int ks = 0; ks < 6; ++ks) {
                int byte = row * 384 + (lk * 8 + ks * 32) * 2; byte ^= (row & 7) << 4;
                hfr[mt][ks] = *(const short8*)((const char*)Bs16 + byte);
            }
        }
        for (int nt = wv; nt < 12; nt += 8) {
            int ncol = nt * 16 + lr;
            const unsigned short* bp = W16 + (size_t)3 * WMAT + (size_t)ncol * DIM + lk * 8;
            f32x4 s0 = {}, s1 = {}, s2 = {}, s3 = {};
#pragma unroll
            for (int ks = 0; ks < 6; ++ks) {
                short8 bf = *(const short8*)(bp + ks * 32);
                s0 = __builtin_amdgcn_mfma_f32_16x16x32_bf16(hfr[0][ks], bf, s0, 0, 0, 0);
                s1 = __builtin_amdgcn_mfma_f32_16x16x32_bf16(hfr[1][ks], bf, s1, 0, 0, 0);
                s2 = __builtin_amdgcn_mfma_f32_16x16x32_bf16(hfr[2][ks], bf, s2, 0, 0, 0);
                s3 = __builtin_amdgcn_mfma_f32_16x16x32_bf16(hfr[3][ks], bf, s3, 0, 0, 0);
            }
            float bia = w2b[ncol];
#pragma unroll
            for (int mt = 0; mt < 4; ++mt) {
                f32x4 ac = (mt == 0) ? s0 : (mt == 1) ? s1 : (mt == 2) ? s2 : s3;
#pragma unroll
                for (int r = 0; r < 4; ++r) {
                    int gr = mt * 16 + lk * 4 + r;
                    if (gr < LL) R2[gr * 196 + ncol] = ac[r] + bia + R2[gr * 196 + ncol];
                }
            }
        }
    }
    __syncthreads();

    // ---- P6: LayerNorm rows of R2 in place ----
    for (int r = wv; r < LL; r += 8) {
        float* p = R2 + r * 196;
        float v0 = p[l], v1 = p[l + 64], v2 = p[l + 128];
        float s = v0 + v1 + v2;
#pragma unroll
        for (int off = 32; off; off >>= 1) s += __shfl_xor(s, off);
        float mu = s * (1.f / DIM);
        float d0 = v0 - mu, d1 = v1 - mu, d2 = v2 - mu;
        float q = d0 * d0 + d1 * d1 + d2 * d2;
#pragma unroll
        for (int off = 32; off; off >>= 1) q += __shfl_xor(q, off);
        float inv = rsqrtf(q * (1.f / DIM) + EPS);
        p[l]       = lng[l] * d0 * inv + lnb[l];
        p[l + 64]  = lng[l + 64] * d1 * inv + lnb[l + 64];
        p[l + 128] = lng[l + 128] * d2 * inv + lnb[l + 128];
    }
    __syncthreads();

    // ---- P7: cvec = [ST, sl, SG] ----
    if (t < DIM) {
        float st = 0.f;
        for (int p = 0; p < LL; ++p) st += was[p] * R2[p * 196 + t];
        cvec[t] = st;
        cvec[DIM + t] = Xs[49 * DIM + t];
        float sg = 0.f;
        for (int lr2 = 0; lr2 < LL; ++lr2) sg += ags[lr2] * Xs[lr2 * DIM + t];
        cvec[2 * DIM + t] = sg;
    }
    __syncthreads();

    // ---- P8: c = normalize(selu(cvec @ wf^T + wf_b)) -> Cb16 global ----
    float cj = 0.f;
    if (t < IDIM) {
        float s = wfb[t];
        const float* wr = wfW + (size_t)t * (3 * DIM);
        for (int e = 0; e < 3 * DIM; e += 4) {
            float4 w4 = *(const float4*)(wr + e);
            s += cvec[e] * w4.x + cvec[e + 1] * w4.y + cvec[e + 2] * w4.z + cvec[e + 3] * w4.w;
        }
        const float sa = 1.6732632423543772f, sc = 1.0507009873554805f;
        cj = sc * (s > 0.f ? s : sa * expm1f(s));
    }
    float sq = cj * cj;
#pragma unroll
    for (int off = 32; off; off >>= 1) sq += __shfl_xor(sq, off);
    if (l == 0) red[wv] = sq;
    __syncthreads();
    if (t < IDIM) {
        float nrm = sqrtf(red[0] + red[1]);
        Cb16g[b * IDIM + t] = f2bf(cj / nrm);
    }
}

// ---------------- Z: block = 64n strip x full 256m, LDS-transposed coalesced stores ----------------
__global__ __launch_bounds__(256) void k_z4(const unsigned short* __restrict__ Cb16,
                                            const unsigned short* __restrict__ emb16,
                                            const float* __restrict__ invn,
                                            float* __restrict__ Z) {
    __shared__ float tr[4][64][68];
    int n0 = blockIdx.x * 64;
    int t = threadIdx.x, w = t >> 6, l = t & 63;
    int lr = l & 15, lk = l >> 4;

    short8 a[4][4];
#pragma unroll
    for (int mt = 0; mt < 4; ++mt) {
        int mrow = w * 64 + mt * 16 + lr;
        const unsigned short* ap = Cb16 + (size_t)mrow * IDIM + lk * 8;
#pragma unroll
        for (int ks = 0; ks < 4; ++ks) a[mt][ks] = *(const short8*)(ap + ks * 32);
    }
    f32x4 acc[4][4] = {};
#pragma unroll
    for (int nt = 0; nt < 4; ++nt) {
        int nrow = n0 + nt * 16 + lr;
        short8 bfr[4];
        if (nrow < NOUT) {
            const unsigned short* bp = emb16 + (size_t)(nrow + 1) * IDIM + lk * 8;
#pragma unroll
            for (int ks = 0; ks < 4; ++ks) bfr[ks] = *(const short8*)(bp + ks * 32);
        } else {
            short8 z = {};
#pragma unroll
            for (int ks = 0; ks < 4; ++ks) bfr[ks] = z;
        }
#pragma unroll
        for (int mt = 0; mt < 4; ++mt)
#pragma unroll
            for (int ks = 0; ks < 4; ++ks)
                acc[mt][nt] = __builtin_amdgcn_mfma_f32_16x16x32_bf16(a[mt][ks], bfr[ks], acc[mt][nt], 0, 0, 0);
    }
#pragma unroll
    for (int nt = 0; nt < 4; ++nt) {
        int gn = n0 + nt * 16 + lr;
        float sc = (gn < NOUT) ? WSC * invn[gn + 1] : 0.f;
#pragma unroll
        for (int mt = 0; mt < 4; ++mt)
#pragma unroll
            for (int r = 0; r < 4; ++r)
                tr[w][mt * 16 + lk * 4 + r][nt * 16 + lr] = acc[mt][nt][r] * sc;
    }
    __syncthreads();
    int q = l >> 4, s = l & 15;
    bool tail = (n0 + 64) > NOUT;
#pragma unroll
    for (int it = 0; it < 16; ++it) {
        int row = it * 4 + q;
        int gm  = w * 64 + row;
        float4 v = *(const float4*)&tr[w][row][s * 4];
        if (!tail) {
            *(float4*)&Z[(size_t)gm * NOUT + n0 + s * 4] = v;
        } else {
            int c0 = n0 + s * 4;
            float vv[4] = {v.x, v.y, v.z, v.w};
#pragma unroll
            for (int j = 0; j < 4; ++j)
                if (c0 + j < NOUT) Z[(size_t)gm * NOUT + c0 + j] = vv[j];
        }
    }
}

extern "C" void kernel_launch(void* const* d_in, const int* in_sizes, int n_in,
                              void* d_out, int out_size, void* d_ws, size_t ws_size,
                              hipStream_t stream) {
    const int*   x     = (const int*)d_in[0];
    const int*   pos   = (const int*)d_in[1];
    const float* emb   = (const float*)d_in[2];
    const float* pose  = (const float*)d_in[3];
    const float* vw0   = (const float*)d_in[4];
    const float* vw1   = (const float*)d_in[5];
    const float* vw2   = (const float*)d_in[6];
    const float* vbias = (const float*)d_in[7];
    const float* w1W   = (const float*)d_in[8];
    const float* w1b   = (const float*)d_in[9];
    const float* w2W   = (const float*)d_in[10];
    const float* w2b   = (const float*)d_in[11];
    const float* wA    = (const float*)d_in[12];
    const float* wg1W  = (const float*)d_in[13];
    const float* wg1b  = (const float*)d_in[14];
    const float* wg2W  = (const float*)d_in[15];
    const float* wg2b  = (const float*)d_in[16];
    const float* gq    = (const float*)d_in[17];
    const float* wfW   = (const float*)d_in[18];
    const float* wfb   = (const float*)d_in[19];
    const float* lng   = (const float*)d_in[20];
    const float* lnb   = (const float*)d_in[21];
    float* Z = (float*)d_out;

    float* w = (float*)d_ws;
    float* scale  = w; w += NITEMS;
    float* invn   = w; w += NITEMS;
    float* pscale = w; w += 64;
    w = (float*)(((uintptr_t)w + 15) & ~(uintptr_t)15);
    unsigned short* emb16 = (unsigned short*)w; w += (size_t)NITEMS * IDIM / 2;
    unsigned short* W16   = (unsigned short*)w; w += (size_t)5 * WMAT / 2;
    unsigned short* Cb16  = (unsigned short*)w; w += (size_t)BB * IDIM / 2;

    k_norms<<<NITEMS / 4, 256, 0, stream>>>(emb, scale, invn, emb16);
    k_pnorms<<<1, 64, 0, stream>>>(pose, pscale);
    k_cvtw<<<5 * 144, 256, 0, stream>>>(vw1, vw2, w1W, w2W, wg1W, W16);
    k_mega<<<BB, 512, 0, stream>>>(x, pos, emb, pose, scale, pscale, W16,
                                   vw0, vbias, w1b, w2b, wg1b, wg2W, wg2b, gq,
                                   wA, lng, lnb, wfW, wfb, Cb16);
    k_z4<<<(NOUT + 63) / 64, 256, 0, stream>>>(Cb16, emb16, invn, Z);
}

// Round 11
// 109.908 us; speedup vs baseline: 3.5865x; 1.1343x over previous
//
#include <hip/hip_runtime.h>
#include <hip/hip_bf16.h>
#include <math.h>
#include <stdint.h>

#define BB 256
#define LL 50
#define IDIM 128
#define PDIM 64
#define DIM 192
#define NITEMS 50000
#define NOUT 49999
#define WSC 20.0f
#define EPS 1e-5f
#define WMAT (DIM * DIM)

typedef __attribute__((ext_vector_type(8))) short  short8;
typedef __attribute__((ext_vector_type(4))) float  f32x4;

__device__ __forceinline__ unsigned short f2bf(float f) {
    unsigned int u = __float_as_uint(f);
    u = (u + 0x7FFFu + ((u >> 16) & 1u)) >> 16;
    return (unsigned short)u;
}
__device__ __forceinline__ float bf2f(unsigned short u) {
    unsigned int v = ((unsigned int)u) << 16;
    return __uint_as_float(v);
}

// ---------------- row norms of emb + bf16 copy ----------------
__global__ __launch_bounds__(256) void k_norms(const float* __restrict__ emb,
                                               float* __restrict__ scale,
                                               float* __restrict__ invn,
                                               unsigned short* __restrict__ emb16) {
    int row  = blockIdx.x * 4 + (threadIdx.x >> 6);
    int lane = threadIdx.x & 63;
    const float* p = emb + (size_t)row * IDIM;
    float a = p[lane], b = p[lane + 64];
    emb16[(size_t)row * IDIM + lane]      = f2bf(a);
    emb16[(size_t)row * IDIM + lane + 64] = f2bf(b);
    float s = a * a + b * b;
#pragma unroll
    for (int off = 32; off; off >>= 1) s += __shfl_xor(s, off);
    if (lane == 0) {
        float n = sqrtf(s);
        scale[row] = fminf(1.0f, 1.5f / fmaxf(n, 1e-7f));
        invn[row]  = (n > 0.f) ? 1.f / n : 0.f;
    }
}

__global__ __launch_bounds__(64) void k_pnorms(const float* __restrict__ pe,
                                               float* __restrict__ pscale) {
    int row = threadIdx.x;
    if (row > LL) return;
    float s = 0.f;
    const float* p = pe + row * PDIM;
    for (int d = 0; d < PDIM; ++d) { float v = p[d]; s += v * v; }
    float n = sqrtf(s);
    pscale[row] = fminf(1.0f, 1.5f / fmaxf(n, 1e-7f));
}

// ---------------- weight convert (+transpose for vw1,vw2) ----------------
// W16 layout: [0]=vw1^T [1]=vw2^T [2]=w1W [3]=w2W [4]=wg1W, each [n][k] 192x192
__global__ __launch_bounds__(256) void k_cvtw(const float* __restrict__ vw1, const float* __restrict__ vw2,
                                              const float* __restrict__ w1W, const float* __restrict__ w2W,
                                              const float* __restrict__ wg1W,
                                              unsigned short* __restrict__ Wout) {
    int b = blockIdx.x;
    int wi = b / 144;
    int pos = (b % 144) * 256 + threadIdx.x;
    int n = pos / DIM, k = pos - n * DIM;
    float v;
    if      (wi == 0) v = vw1[(size_t)k * DIM + n];
    else if (wi == 1) v = vw2[(size_t)k * DIM + n];
    else if (wi == 2) v = w1W[pos];
    else if (wi == 3) v = w2W[pos];
    else              v = wg1W[pos];
    Wout[(size_t)wi * WMAT + pos] = f2bf(v);
}

// ================= MEGAKERNEL =================
__global__ __launch_bounds__(512) void k_mega(
    const int* __restrict__ x, const int* __restrict__ pos,
    const float* __restrict__ emb, const float* __restrict__ pe,
    const float* __restrict__ scale, const float* __restrict__ pscale,
    const unsigned short* __restrict__ W16,
    const float* __restrict__ vw0, const float* __restrict__ vbias,
    const float* __restrict__ w1b, const float* __restrict__ w2b,
    const float* __restrict__ wg1b, const float* __restrict__ wg2W,
    const float* __restrict__ wg2b, const float* __restrict__ gq,
    const float* __restrict__ wA, const float* __restrict__ lng,
    const float* __restrict__ lnb, const float* __restrict__ wfW,
    const float* __restrict__ wfb, unsigned short* __restrict__ Cb16g) {

    __shared__ unsigned short Bs16[64 * DIM];   // 24576 B swizzled: X16 -> S16 -> H16
    __shared__ unsigned short X16T[DIM * 72];   // 27648 B X^T bf16 [d][j], cols 50..63 zero
    __shared__ unsigned short Ab16[64 * 72];    //  9216 B attn weights bf16 [i][j]
    __shared__ float R1[LL * 196];              // 39200 B: K' -> parts[8][12][64]
    __shared__ float R2[LL * 196];              // 39200 B: Q -> S -> S2/S3
    __shared__ float xlast[DIM];
    __shared__ float GLs[DIM];
    __shared__ float cvec[3 * DIM];
    __shared__ float red2[4][128];
    __shared__ float ags[64];
    __shared__ int   msk[64];
    __shared__ float was[64];
    __shared__ float red[8];
    __shared__ int   xi[LL], pii[LL];
    __shared__ float xsc[LL], psc[LL];

    const int b = blockIdx.x, t = threadIdx.x;
    const int wv = t >> 6, l = t & 63;
    const int lr = l & 15, lk = l >> 4;

    // ---- P0: indices, consts ----
    if (t < LL) {
        int v = x[b * LL + t];  xi[t] = v;  xsc[t] = scale[v];
        int pv = pos[b * LL + t]; pii[t] = pv; psc[t] = pscale[pv];
    }
    if (t >= 64 && t < 128) ags[t - 64] = 0.f;
    if (t >= 128 && t < 128 + LL) was[t - 128] = wA[t - 128];
    __syncthreads();
    if (t < 64) msk[t] = (t < LL) ? xi[t] : 0;
    // gather: wave per row, lane = d
    for (int r = wv; r < LL; r += 8) {
        float sx = xsc[r], sp = psc[r];
        float v0 = emb[(size_t)xi[r] * IDIM + l] * sx;
        float v1 = emb[(size_t)xi[r] * IDIM + l + 64] * sx;
        float v2 = pe[pii[r] * PDIM + l] * sp;
        int base = r * 384, sw = (r & 7) << 4;
        *(unsigned short*)((char*)Bs16 + ((base + l * 2) ^ sw))         = f2bf(v0);
        *(unsigned short*)((char*)Bs16 + ((base + (l + 64) * 2) ^ sw))  = f2bf(v1);
        *(unsigned short*)((char*)Bs16 + ((base + (l + 128) * 2) ^ sw)) = f2bf(v2);
        X16T[l * 72 + r]         = f2bf(v0);
        X16T[(l + 64) * 72 + r]  = f2bf(v1);
        X16T[(l + 128) * 72 + r] = f2bf(v2);
        if (r == 49) { xlast[l] = v0; xlast[l + 64] = v1; xlast[l + 128] = v2; }
    }
    // zero pads: Bs16 rows 50-63, X16T cols 50-63, Ab16 rows 50-63
    for (int e = t; e < 14 * DIM; e += 512) Bs16[LL * DIM + e] = 0;
    for (int e = t; e < DIM * 14; e += 512) { int d = e / 14, j = 50 + (e - d * 14); X16T[d * 72 + j] = 0; }
    for (int e = t; e < 14 * 72; e += 512) Ab16[50 * 72 + e] = 0;
    __syncthreads();

    // ---- GL = xlast @ wg2W^T + wg2b ----
    if (t < DIM) {
        float g = wg2b[t];
        const float* wr = wg2W + (size_t)t * DIM;
        float s0 = 0, s1 = 0, s2 = 0, s3 = 0;
        for (int k = 0; k < DIM; k += 4) {
            float4 w4 = *(const float4*)(wr + k);
            s0 += xlast[k] * w4.x; s1 += xlast[k + 1] * w4.y;
            s2 += xlast[k + 2] * w4.z; s3 += xlast[k + 3] * w4.w;
        }
        GLs[t] = g + ((s0 + s1) + (s2 + s3));
    }
    __syncthreads();

    // ---- P1: three GEMMs sharing A = X16 (swizzled): K'->R1, Q->R2, Gpre->ags ----
    {
        short8 afr[4][6];
#pragma unroll
        for (int mt = 0; mt < 4; ++mt) {
            int row = mt * 16 + lr;
#pragma unroll
            for (int ks = 0; ks < 6; ++ks) {
                int byte = (row * 384 + (lk * 8 + ks * 32) * 2) ^ ((row & 7) << 4);
                afr[mt][ks] = *(const short8*)((const char*)Bs16 + byte);
            }
        }
        for (int task = wv; task < 36; task += 8) {
            int out = task / 12, nt = task % 12;
            int ncol = nt * 16 + lr;
            const unsigned short* bp = W16 + (size_t)(out == 0 ? 0 : (out == 1 ? 1 : 4)) * WMAT
                                       + (size_t)ncol * DIM + lk * 8;
            f32x4 a0 = {}, a1 = {}, a2 = {}, a3 = {};
#pragma unroll
            for (int ks = 0; ks < 6; ++ks) {
                short8 bf = *(const short8*)(bp + ks * 32);
                a0 = __builtin_amdgcn_mfma_f32_16x16x32_bf16(afr[0][ks], bf, a0, 0, 0, 0);
                a1 = __builtin_amdgcn_mfma_f32_16x16x32_bf16(afr[1][ks], bf, a1, 0, 0, 0);
                a2 = __builtin_amdgcn_mfma_f32_16x16x32_bf16(afr[2][ks], bf, a2, 0, 0, 0);
                a3 = __builtin_amdgcn_mfma_f32_16x16x32_bf16(afr[3][ks], bf, a3, 0, 0, 0);
            }
            if (out == 0) {
                float bia = vbias[ncol];
#pragma unroll
                for (int mt = 0; mt < 4; ++mt) {
                    f32x4 ac = (mt == 0) ? a0 : (mt == 1) ? a1 : (mt == 2) ? a2 : a3;
#pragma unroll
                    for (int r = 0; r < 4; ++r) {
                        int gr = mt * 16 + lk * 4 + r;
                        if (gr < LL) R1[gr * 196 + ncol] = ac[r] + bia;
                    }
                }
            } else if (out == 1) {
#pragma unroll
                for (int mt = 0; mt < 4; ++mt) {
                    f32x4 ac = (mt == 0) ? a0 : (mt == 1) ? a1 : (mt == 2) ? a2 : a3;
#pragma unroll
                    for (int r = 0; r < 4; ++r) {
                        int gr = mt * 16 + lk * 4 + r;
                        if (gr < LL) R2[gr * 196 + ncol] = ac[r];
                    }
                }
            } else {
                float bia = wg1b[ncol] + GLs[ncol];
                float gqv = gq[ncol];
#pragma unroll
                for (int mt = 0; mt < 4; ++mt) {
                    f32x4 ac = (mt == 0) ? a0 : (mt == 1) ? a1 : (mt == 2) ? a2 : a3;
                    int gr0 = mt * 16 + lk * 4;
                    float v0 = ac[0] + bia, v1 = ac[1] + bia, v2 = ac[2] + bia, v3 = ac[3] + bia;
                    float c0 = (gr0 + 0 < LL) ? gqv / (1.f + expf(-v0)) : 0.f;
                    float c1 = (gr0 + 1 < LL) ? gqv / (1.f + expf(-v1)) : 0.f;
                    float c2 = (gr0 + 2 < LL) ? gqv / (1.f + expf(-v2)) : 0.f;
                    float c3 = (gr0 + 3 < LL) ? gqv / (1.f + expf(-v3)) : 0.f;
#pragma unroll
                    for (int off = 1; off < 16; off <<= 1) {
                        c0 += __shfl_xor(c0, off); c1 += __shfl_xor(c1, off);
                        c2 += __shfl_xor(c2, off); c3 += __shfl_xor(c3, off);
                    }
                    if (lr == 0) {
                        if (gr0 + 0 < LL) atomicAdd(&ags[gr0 + 0], c0);
                        if (gr0 + 1 < LL) atomicAdd(&ags[gr0 + 1], c1);
                        if (gr0 + 2 < LL) atomicAdd(&ags[gr0 + 2], c2);
                        if (gr0 + 3 < LL) atomicAdd(&ags[gr0 + 3], c3);
                    }
                }
            }
        }
    }
    __syncthreads();

    // ---- P2: alpha + masked softmax -> Ab16 ----
    {
        const int d0 = wv * 24;
        float kr[24], wr[24];
        {
            const float* wp = vw0 + d0;
#pragma unroll
            for (int q = 0; q < 6; ++q) {
                float4 v = *(const float4*)(wp + q * 4);
                wr[q * 4] = v.x; wr[q * 4 + 1] = v.y; wr[q * 4 + 2] = v.z; wr[q * 4 + 3] = v.w;
            }
            if (l < LL) {
                const float* kp = R1 + l * 196 + d0;
#pragma unroll
                for (int q = 0; q < 6; ++q) {
                    float4 v = *(const float4*)(kp + q * 4);
                    kr[q * 4] = v.x; kr[q * 4 + 1] = v.y; kr[q * 4 + 2] = v.z; kr[q * 4 + 3] = v.w;
                }
            } else {
#pragma unroll
                for (int q = 0; q < 24; ++q) kr[q] = 0.f;
            }
        }
        __syncthreads();   // kr cached; R1 free -> parts
        float* parts = R1;              // [8][12][64]
        const float NEG = -__builtin_inff();
        bool valid = (l < LL) && (msk[l] != 0);
        for (int i0 = 0; i0 < LL; i0 += 12) {
            int cnt = (i0 + 12 <= LL) ? 12 : (LL - i0);
            for (int i = 0; i < cnt; ++i) {
                const float* qrow = R2 + (i0 + i) * 196 + d0;
                float b0 = 0, b1 = 0, b2 = 0, b3 = 0;
#pragma unroll
                for (int q = 0; q < 6; ++q) {
                    float4 qv = *(const float4*)(qrow + q * 4);
                    b0 += fmaxf(kr[q * 4 + 0] + qv.x, 0.f) * wr[q * 4 + 0];
                    b1 += fmaxf(kr[q * 4 + 1] + qv.y, 0.f) * wr[q * 4 + 1];
                    b2 += fmaxf(kr[q * 4 + 2] + qv.z, 0.f) * wr[q * 4 + 2];
                    b3 += fmaxf(kr[q * 4 + 3] + qv.w, 0.f) * wr[q * 4 + 3];
                }
                parts[(wv * 12 + i) * 64 + l] = (b0 + b1) + (b2 + b3);
            }
            __syncthreads();
            for (int i = wv; i < cnt; i += 8) {
                float aj = 0.f;
#pragma unroll
                for (int w2 = 0; w2 < 8; ++w2) aj += parts[(w2 * 12 + i) * 64 + l];
                if (!valid) aj = NEG;
                float m = aj;
#pragma unroll
                for (int off = 32; off; off >>= 1) m = fmaxf(m, __shfl_xor(m, off));
                float e = valid ? expf(aj - m) : 0.f;
                float s = e;
#pragma unroll
                for (int off = 32; off; off >>= 1) s += __shfl_xor(s, off);
                Ab16[(i0 + i) * 72 + l] = f2bf(e / s);   // 0 for l>=LL
            }
            __syncthreads();
        }
    }

    // ---- P3: S = Ab @ X via MFMA (A=Ab16, B=X16T) -> R2 f32 + Bs16 bf16 ----
    for (int task = wv; task < 48; task += 8) {
        int mt = task / 12, nt = task - (task / 12) * 12;
        int i0 = mt * 16, d0c = nt * 16;
        short8 aA0 = *(const short8*)(Ab16 + (i0 + lr) * 72 + lk * 8);
        short8 aA1 = *(const short8*)(Ab16 + (i0 + lr) * 72 + 32 + lk * 8);
        short8 bB0 = *(const short8*)(X16T + (d0c + lr) * 72 + lk * 8);
        short8 bB1 = *(const short8*)(X16T + (d0c + lr) * 72 + 32 + lk * 8);
        f32x4 ac = {};
        ac = __builtin_amdgcn_mfma_f32_16x16x32_bf16(aA0, bB0, ac, 0, 0, 0);
        ac = __builtin_amdgcn_mfma_f32_16x16x32_bf16(aA1, bB1, ac, 0, 0, 0);
        int d = d0c + lr;
#pragma unroll
        for (int r = 0; r < 4; ++r) {
            int i = i0 + lk * 4 + r;
            if (i < LL) {
                R2[i * 196 + d] = ac[r];
                int byte = (i * 384 + d * 2) ^ ((i & 7) << 4);
                *(unsigned short*)((char*)Bs16 + byte) = f2bf(ac[r]);
            }
        }
    }
    __syncthreads();

    // ---- P4: H2 = relu(S@w1 + b) -> Bs16 ----
    {
        short8 sfr[4][6];
#pragma unroll
        for (int mt = 0; mt < 4; ++mt) {
            int row = mt * 16 + lr;
#pragma unroll
            for (int ks = 0; ks < 6; ++ks) {
                int byte = (row * 384 + (lk * 8 + ks * 32) * 2) ^ ((row & 7) << 4);
                sfr[mt][ks] = *(const short8*)((const char*)Bs16 + byte);
            }
        }
        f32x4 h0[4] = {}, h1[4] = {};
        {
            int ncol = wv * 16 + lr;
            const unsigned short* bp = W16 + (size_t)2 * WMAT + (size_t)ncol * DIM + lk * 8;
#pragma unroll
            for (int ks = 0; ks < 6; ++ks) {
                short8 bf = *(const short8*)(bp + ks * 32);
                h0[0] = __builtin_amdgcn_mfma_f32_16x16x32_bf16(sfr[0][ks], bf, h0[0], 0, 0, 0);
                h0[1] = __builtin_amdgcn_mfma_f32_16x16x32_bf16(sfr[1][ks], bf, h0[1], 0, 0, 0);
                h0[2] = __builtin_amdgcn_mfma_f32_16x16x32_bf16(sfr[2][ks], bf, h0[2], 0, 0, 0);
                h0[3] = __builtin_amdgcn_mfma_f32_16x16x32_bf16(sfr[3][ks], bf, h0[3], 0, 0, 0);
            }
        }
        if (wv < 4) {
            int ncol = (wv + 8) * 16 + lr;
            const unsigned short* bp = W16 + (size_t)2 * WMAT + (size_t)ncol * DIM + lk * 8;
#pragma unroll
            for (int ks = 0; ks < 6; ++ks) {
                short8 bf = *(const short8*)(bp + ks * 32);
                h1[0] = __builtin_amdgcn_mfma_f32_16x16x32_bf16(sfr[0][ks], bf, h1[0], 0, 0, 0);
                h1[1] = __builtin_amdgcn_mfma_f32_16x16x32_bf16(sfr[1][ks], bf, h1[1], 0, 0, 0);
                h1[2] = __builtin_amdgcn_mfma_f32_16x16x32_bf16(sfr[2][ks], bf, h1[2], 0, 0, 0);
                h1[3] = __builtin_amdgcn_mfma_f32_16x16x32_bf16(sfr[3][ks], bf, h1[3], 0, 0, 0);
            }
        }
        __syncthreads();   // all S16 reads done
        {
            int gc = wv * 16 + lr;
            float bia = w1b[gc];
#pragma unroll
            for (int mt = 0; mt < 4; ++mt)
#pragma unroll
                for (int r = 0; r < 4; ++r) {
                    int gr = mt * 16 + lk * 4 + r;
                    if (gr < LL) {
                        float v = fmaxf(h0[mt][r] + bia, 0.f);
                        int byte = (gr * 384 + gc * 2) ^ ((gr & 7) << 4);
                        *(unsigned short*)((char*)Bs16 + byte) = f2bf(v);
                    }
                }
        }
        if (wv < 4) {
            int gc = (wv + 8) * 16 + lr;
            float bia = w1b[gc];
#pragma unroll
            for (int mt = 0; mt < 4; ++mt)
#pragma unroll
                for (int r = 0; r < 4; ++r) {
                    int gr = mt * 16 + lk * 4 + r;
                    if (gr < LL) {
                        float v = fmaxf(h1[mt][r] + bia, 0.f);
                        int byte = (gr * 384 + gc * 2) ^ ((gr & 7) << 4);
                        *(unsigned short*)((char*)Bs16 + byte) = f2bf(v);
                    }
                }
        }
    }
    __syncthreads();

    // ---- P5: S2 = H2@w2 + b + S (residual in-place in R2) ----
    {
        short8 hfr[4][6];
#pragma unroll
        for (int mt = 0; mt < 4; ++mt) {
            int row = mt * 16 + lr;
#pragma unroll
            for (int ks = 0; ks < 6; ++ks) {
                int byte = (row * 384 + (lk * 8 + ks * 32) * 2) ^ ((row & 7) << 4);
                hfr[mt][ks] = *(const short8*)((const char*)Bs16 + byte);
            }
        }
        for (int nt = wv; nt < 12; nt += 8) {
            int ncol = nt * 16 + lr;
            const unsigned short* bp = W16 + (size_t)3 * WMAT + (size_t)ncol * DIM + lk * 8;
            f32x4 s0 = {}, s1 = {}, s2 = {}, s3 = {};
#pragma unroll
            for (int ks = 0; ks < 6; ++ks) {
                short8 bf = *(const short8*)(bp + ks * 32);
                s0 = __builtin_amdgcn_mfma_f32_16x16x32_bf16(hfr[0][ks], bf, s0, 0, 0, 0);
                s1 = __builtin_amdgcn_mfma_f32_16x16x32_bf16(hfr[1][ks], bf, s1, 0, 0, 0);
                s2 = __builtin_amdgcn_mfma_f32_16x16x32_bf16(hfr[2][ks], bf, s2, 0, 0, 0);
                s3 = __builtin_amdgcn_mfma_f32_16x16x32_bf16(hfr[3][ks], bf, s3, 0, 0, 0);
            }
            float bia = w2b[ncol];
#pragma unroll
            for (int mt = 0; mt < 4; ++mt) {
                f32x4 ac = (mt == 0) ? s0 : (mt == 1) ? s1 : (mt == 2) ? s2 : s3;
#pragma unroll
                for (int r = 0; r < 4; ++r) {
                    int gr = mt * 16 + lk * 4 + r;
                    if (gr < LL) R2[gr * 196 + ncol] = ac[r] + bia + R2[gr * 196 + ncol];
                }
            }
        }
    }
    __syncthreads();

    // ---- P6: LayerNorm rows of R2 in place ----
    for (int r = wv; r < LL; r += 8) {
        float* p = R2 + r * 196;
        float v0 = p[l], v1 = p[l + 64], v2 = p[l + 128];
        float s = v0 + v1 + v2;
#pragma unroll
        for (int off = 32; off; off >>= 1) s += __shfl_xor(s, off);
        float mu = s * (1.f / DIM);
        float d0 = v0 - mu, d1 = v1 - mu, d2 = v2 - mu;
        float q = d0 * d0 + d1 * d1 + d2 * d2;
#pragma unroll
        for (int off = 32; off; off >>= 1) q += __shfl_xor(q, off);
        float inv = rsqrtf(q * (1.f / DIM) + EPS);
        p[l]       = lng[l] * d0 * inv + lnb[l];
        p[l + 64]  = lng[l + 64] * d1 * inv + lnb[l + 64];
        p[l + 128] = lng[l + 128] * d2 * inv + lnb[l + 128];
    }
    __syncthreads();

    // ---- P7: cvec = [ST, sl, SG]  (ST on waves 0-2, SG on waves 5-7) ----
    if (t < DIM) {
        float st = 0.f;
        for (int p = 0; p < LL; ++p) st += was[p] * R2[p * 196 + t];
        cvec[t] = st;
        cvec[DIM + t] = xlast[t];
    } else if (t >= 320) {
        int d = t - 320;
        float sg = 0.f;
        const unsigned short* xr = X16T + d * 72;
        for (int p = 0; p < LL; ++p) sg += ags[p] * bf2f(xr[p]);
        cvec[2 * DIM + d] = sg;
    }
    __syncthreads();

    // ---- P8: c = normalize(selu(cvec @ wf^T + wf_b)) -> Cb16 global ----
    {
        int out = t & 127, part = t >> 7;
        float s = (part == 0) ? wfb[out] : 0.f;
        const float* wr = wfW + (size_t)out * (3 * DIM) + part * 144;
        const float* cv = cvec + part * 144;
        for (int e = 0; e < 144; e += 4) {
            float4 w4 = *(const float4*)(wr + e);
            s += cv[e] * w4.x + cv[e + 1] * w4.y + cv[e + 2] * w4.z + cv[e + 3] * w4.w;
        }
        red2[part][out] = s;
    }
    __syncthreads();
    float cj = 0.f;
    if (t < IDIM) {
        float s = red2[0][t] + red2[1][t] + red2[2][t] + red2[3][t];
        const float sa = 1.6732632423543772f, sc = 1.0507009873554805f;
        cj = sc * (s > 0.f ? s : sa * expm1f(s));
    }
    float sq = cj * cj;
#pragma unroll
    for (int off = 32; off; off >>= 1) sq += __shfl_xor(sq, off);
    if (l == 0) red[wv] = sq;
    __syncthreads();
    if (t < IDIM) {
        float nrm = sqrtf(red[0] + red[1]);
        Cb16g[b * IDIM + t] = f2bf(cj / nrm);
    }
}

// ---------------- Z: block = 64n strip x full 256m, LDS-transposed coalesced stores ----------------
__global__ __launch_bounds__(256) void k_z4(const unsigned short* __restrict__ Cb16,
                                            const unsigned short* __restrict__ emb16,
                                            const float* __restrict__ invn,
                                            float* __restrict__ Z) {
    __shared__ float tr[4][64][68];
    int n0 = blockIdx.x * 64;
    int t = threadIdx.x, w = t >> 6, l = t & 63;
    int lr = l & 15, lk = l >> 4;

    short8 a[4][4];
#pragma unroll
    for (int mt = 0; mt < 4; ++mt) {
        int mrow = w * 64 + mt * 16 + lr;
        const unsigned short* ap = Cb16 + (size_t)mrow * IDIM + lk * 8;
#pragma unroll
        for (int ks = 0; ks < 4; ++ks) a[mt][ks] = *(const short8*)(ap + ks * 32);
    }
    f32x4 acc[4][4] = {};
#pragma unroll
    for (int nt = 0; nt < 4; ++nt) {
        int nrow = n0 + nt * 16 + lr;
        short8 bfr[4];
        if (nrow < NOUT) {
            const unsigned short* bp = emb16 + (size_t)(nrow + 1) * IDIM + lk * 8;
#pragma unroll
            for (int ks = 0; ks < 4; ++ks) bfr[ks] = *(const short8*)(bp + ks * 32);
        } else {
            short8 z = {};
#pragma unroll
            for (int ks = 0; ks < 4; ++ks) bfr[ks] = z;
        }
#pragma unroll
        for (int mt = 0; mt < 4; ++mt)
#pragma unroll
            for (int ks = 0; ks < 4; ++ks)
                acc[mt][nt] = __builtin_amdgcn_mfma_f32_16x16x32_bf16(a[mt][ks], bfr[ks], acc[mt][nt], 0, 0, 0);
    }
#pragma unroll
    for (int nt = 0; nt < 4; ++nt) {
        int gn = n0 + nt * 16 + lr;
        float sc = (gn < NOUT) ? WSC * invn[gn + 1] : 0.f;
#pragma unroll
        for (int mt = 0; mt < 4; ++mt)
#pragma unroll
            for (int r = 0; r < 4; ++r)
                tr[w][mt * 16 + lk * 4 + r][nt * 16 + lr] = acc[mt][nt][r] * sc;
    }
    __syncthreads();
    int q = l >> 4, s = l & 15;
    bool tail = (n0 + 64) > NOUT;
#pragma unroll
    for (int it = 0; it < 16; ++it) {
        int row = it * 4 + q;
        int gm  = w * 64 + row;
        float4 v = *(const float4*)&tr[w][row][s * 4];
        if (!tail) {
            *(float4*)&Z[(size_t)gm * NOUT + n0 + s * 4] = v;
        } else {
            int c0 = n0 + s * 4;
            float vv[4] = {v.x, v.y, v.z, v.w};
#pragma unroll
            for (int j = 0; j < 4; ++j)
                if (c0 + j < NOUT) Z[(size_t)gm * NOUT + c0 + j] = vv[j];
        }
    }
}

extern "C" void kernel_launch(void* const* d_in, const int* in_sizes, int n_in,
                              void* d_out, int out_size, void* d_ws, size_t ws_size,
                              hipStream_t stream) {
    const int*   x     = (const int*)d_in[0];
    const int*   pos   = (const int*)d_in[1];
    const float* emb   = (const float*)d_in[2];
    const float* pose  = (const float*)d_in[3];
    const float* vw0   = (const float*)d_in[4];
    const float* vw1   = (const float*)d_in[5];
    const float* vw2   = (const float*)d_in[6];
    const float* vbias = (const float*)d_in[7];
    const float* w1W   = (const float*)d_in[8];
    const float* w1b   = (const float*)d_in[9];
    const float* w2W   = (const float*)d_in[10];
    const float* w2b   = (const float*)d_in[11];
    const float* wA    = (const float*)d_in[12];
    const float* wg1W  = (const float*)d_in[13];
    const float* wg1b  = (const float*)d_in[14];
    const float* wg2W  = (const float*)d_in[15];
    const float* wg2b  = (const float*)d_in[16];
    const float* gq    = (const float*)d_in[17];
    const float* wfW   = (const float*)d_in[18];
    const float* wfb   = (const float*)d_in[19];
    const float* lng   = (const float*)d_in[20];
    const float* lnb   = (const float*)d_in[21];
    float* Z = (float*)d_out;

    float* w = (float*)d_ws;
    float* scale  = w; w += NITEMS;
    float* invn   = w; w += NITEMS;
    float* pscale = w; w += 64;
    w = (float*)(((uintptr_t)w + 15) & ~(uintptr_t)15);
    unsigned short* emb16 = (unsigned short*)w; w += (size_t)NITEMS * IDIM / 2;
    unsigned short* W16   = (unsigned short*)w; w += (size_t)5 * WMAT / 2;
    unsigned short* Cb16  = (unsigned short*)w; w += (size_t)BB * IDIM / 2;

    k_norms<<<NITEMS / 4, 256, 0, stream>>>(emb, scale, invn, emb16);
    k_pnorms<<<1, 64, 0, stream>>>(pose, pscale);
    k_cvtw<<<5 * 144, 256, 0, stream>>>(vw1, vw2, w1W, w2W, wg1W, W16);
    k_mega<<<BB, 512, 0, stream>>>(x, pos, emb, pose, scale, pscale, W16,
                                   vw0, vbias, w1b, w2b, wg1b, wg2W, wg2b, gq,
                                   wA, lng, lnb, wfW, wfb, Cb16);
    k_z4<<<(NOUT + 63) / 64, 256, 0, stream>>>(Cb16, emb16, invn, Z);
}